// Round 1
// baseline (3054.011 us; speedup 1.0000x reference)
//
#include <hip/hip_runtime.h>
#include <hip/hip_bf16.h>
#include <math.h>

#define HIDDEN 100

// ---------------------------------------------------------------------------
// Fused 2-layer MLP: out = relu(X @ W1 + b1) @ W2 + b2
// Weights staged in LDS (~88 KB -> 1 block/CU). Each block processes 2 rows
// per iteration (128 threads per row).
// STORE: write output rows to Y. NORM: accumulate mean ||out - REF||_row.
// ---------------------------------------------------------------------------
template<int DIN, int DOUT, bool STORE, bool NORM>
__global__ __launch_bounds__(256, 1) void mlp_kernel(
    const float* __restrict__ X,
    const float* __restrict__ W1, const float* __restrict__ B1,
    const float* __restrict__ W2, const float* __restrict__ B2,
    float* __restrict__ Y, const float* __restrict__ REF,
    float* __restrict__ out, float inv_n, int N)
{
    __shared__ float w1s[DIN * HIDDEN];
    __shared__ float w2s[HIDDEN * DOUT];
    __shared__ float xs[2][DIN];
    __shared__ float hs[2][HIDDEN];
    __shared__ float red[2][2];

    const int tid = threadIdx.x;
    for (int i = tid; i < DIN * HIDDEN; i += 256) w1s[i] = W1[i];
    for (int i = tid; i < HIDDEN * DOUT; i += 256) w2s[i] = W2[i];

    const int slot = tid >> 7;      // which of the 2 concurrent rows
    const int lane = tid & 127;     // thread within row-group
    const int wv   = lane >> 6;     // wave within row-group (0/1)
    const int ln   = lane & 63;     // lane within wave
    float acc = 0.f;                // per-block norm accumulator (lane==0)

    __syncthreads();

    for (int row0 = blockIdx.x * 2; row0 < N; row0 += gridDim.x * 2) {
        const int row = row0 + slot;   // N is even -> always valid
        for (int i = lane; i < DIN; i += 128)
            xs[slot][i] = X[(size_t)row * DIN + i];
        __syncthreads();

        if (lane < HIDDEN) {
            float h = B1[lane];
            #pragma unroll 4
            for (int i = 0; i < DIN; i++)
                h = fmaf(xs[slot][i], w1s[i * HIDDEN + lane], h);
            hs[slot][lane] = fmaxf(h, 0.f);
        }
        __syncthreads();

        float nsum = 0.f;
        if (lane < DOUT) {
            float o = B2[lane];
            #pragma unroll 4
            for (int i = 0; i < HIDDEN; i++)
                o = fmaf(hs[slot][i], w2s[i * DOUT + lane], o);
            if (STORE) Y[(size_t)row * DOUT + lane] = o;
            if (NORM) {
                float d = o - REF[(size_t)row * DOUT + lane];
                nsum = d * d;
            }
        }
        if (NORM) {
            #pragma unroll
            for (int o = 32; o > 0; o >>= 1) nsum += __shfl_down(nsum, o);
            if (ln == 0) red[slot][wv] = nsum;
            __syncthreads();
            if (lane == 0) acc += sqrtf(red[slot][0] + red[slot][1]);
        }
        __syncthreads();   // protect xs/hs/red reuse
    }
    if (NORM && lane == 0) atomicAdd(out, acc * inv_n);
}

// ---------------------------------------------------------------------------
// Row squared-norms of the two target matrices (wave per row, coalesced).
// ---------------------------------------------------------------------------
__global__ __launch_bounds__(256) void norms_kernel(
    const float* __restrict__ Y, float* __restrict__ tny,
    const float* __restrict__ X, float* __restrict__ tnx, int N)
{
    const int gw = (int)((blockIdx.x * blockDim.x + threadIdx.x) >> 6);
    const int ln = threadIdx.x & 63;
    float s = 0.f;
    if (gw < N) {
        const float* p = Y + (size_t)gw * 120;
        for (int d = ln; d < 120; d += 64) s = fmaf(p[d], p[d], s);
        #pragma unroll
        for (int o = 32; o > 0; o >>= 1) s += __shfl_down(s, o);
        if (ln == 0) tny[gw] = s;
    } else if (gw < 2 * N) {
        const int r = gw - N;
        const float* p = X + (size_t)r * 100;
        for (int d = ln; d < 100; d += 64) s = fmaf(p[d], p[d], s);
        #pragma unroll
        for (int o = 32; o > 0; o >>= 1) s += __shfl_down(s, o);
        if (ln == 0) tnx[r] = s;
    }
}

// ---------------------------------------------------------------------------
// sup_x + sup_y: per-pair distance norms, one thread per pair.
// ---------------------------------------------------------------------------
__global__ __launch_bounds__(256) void sup_kernel(
    const float* __restrict__ xm, const float* __restrict__ ym,
    const float* __restrict__ xw, const float* __restrict__ yw,
    const int* __restrict__ im, int K, float* __restrict__ out, float inv_k)
{
    const int k = blockIdx.x * blockDim.x + threadIdx.x;
    float s = 0.f;
    if (k < K) {
        const int xi = im[2 * k], yi = im[2 * k + 1];
        const float* a = xm + (size_t)xi * 120;
        const float* b = yw + (size_t)yi * 120;
        float s1 = 0.f;
        for (int d = 0; d < 120; d++) { float df = a[d] - b[d]; s1 = fmaf(df, df, s1); }
        const float* c = ym + (size_t)yi * 100;
        const float* e = xw + (size_t)xi * 100;
        float s2 = 0.f;
        for (int d = 0; d < 100; d++) { float df = c[d] - e[d]; s2 = fmaf(df, df, s2); }
        s = sqrtf(s1) + sqrtf(s2);
    }
    #pragma unroll
    for (int o = 32; o > 0; o >>= 1) s += __shfl_down(s, o);
    if ((threadIdx.x & 63) == 0 && s != 0.f) atomicAdd(out, s * inv_k);
}

// ---------------------------------------------------------------------------
// 1-NN search: for each of 64 gathered A-rows, find argmin_j over a chunk of
// target rows of (|t_j|^2 - 2 a.t_j). Register-blocked 64x64 GEMM tiles,
// 4x4 micro-tile per thread, float4 LDS reads (padded stride -> 2-way max).
// Partial (min,argmin) per (k, chunk) written to workspace.
// ---------------------------------------------------------------------------
template<int D, int LDT>
__global__ __launch_bounds__(256, 2) void nn_kernel(
    const float* __restrict__ MAP,
    const int* __restrict__ gidx, int goff,
    const float* __restrict__ T, const float* __restrict__ tn, int Ntgt,
    float* __restrict__ pmin, int* __restrict__ pidx,
    int NC, int chunk_len)
{
    __shared__ float As[64 * LDT];
    __shared__ float Bs[64 * LDT];
    __shared__ float redm[64 * 16];
    __shared__ int   redi[64 * 16];

    const int tid = threadIdx.x;
    const int tx = tid & 15, ty = tid >> 4;
    const int k0 = blockIdx.x * 64;
    const int cid = blockIdx.y;
    const int jstart = cid * chunk_len;
    int jend = jstart + chunk_len; if (jend > Ntgt) jend = Ntgt;
    constexpr int KPF = D / 4;

    // Load gathered A tile (64 rows x D)
    for (int t = tid; t < 64 * KPF; t += 256) {
        const int r = t / KPF, c = t - r * KPF;
        const int src = gidx[(k0 + r) * 2 + goff];
        const float4 v = reinterpret_cast<const float4*>(MAP + (size_t)src * D)[c];
        *reinterpret_cast<float4*>(&As[r * LDT + 4 * c]) = v;
    }

    float m[4]  = { __builtin_inff(), __builtin_inff(), __builtin_inff(), __builtin_inff() };
    int   am[4] = { 0x7fffffff, 0x7fffffff, 0x7fffffff, 0x7fffffff };

    for (int jt = jstart; jt < jend; jt += 64) {
        __syncthreads();
        for (int t = tid; t < 64 * KPF; t += 256) {
            const int r = t / KPF, c = t - r * KPF;
            const int j = jt + r;
            if (j < jend) {
                const float4 v = reinterpret_cast<const float4*>(T + (size_t)j * D)[c];
                *reinterpret_cast<float4*>(&Bs[r * LDT + 4 * c]) = v;
            }
        }
        __syncthreads();

        float c4[4][4];
        #pragma unroll
        for (int i = 0; i < 4; i++)
            #pragma unroll
            for (int jj = 0; jj < 4; jj++) c4[i][jj] = 0.f;

        #pragma unroll 3
        for (int d = 0; d < D; d += 4) {
            const float4 a0 = *reinterpret_cast<const float4*>(&As[(4 * ty + 0) * LDT + d]);
            const float4 a1 = *reinterpret_cast<const float4*>(&As[(4 * ty + 1) * LDT + d]);
            const float4 a2 = *reinterpret_cast<const float4*>(&As[(4 * ty + 2) * LDT + d]);
            const float4 a3 = *reinterpret_cast<const float4*>(&As[(4 * ty + 3) * LDT + d]);
            const float4 b0 = *reinterpret_cast<const float4*>(&Bs[(tx +  0) * LDT + d]);
            const float4 b1 = *reinterpret_cast<const float4*>(&Bs[(tx + 16) * LDT + d]);
            const float4 b2 = *reinterpret_cast<const float4*>(&Bs[(tx + 32) * LDT + d]);
            const float4 b3 = *reinterpret_cast<const float4*>(&Bs[(tx + 48) * LDT + d]);
            #define DOT4(cc, aa, bb) \
                cc = fmaf(aa.x, bb.x, fmaf(aa.y, bb.y, fmaf(aa.z, bb.z, fmaf(aa.w, bb.w, cc))))
            DOT4(c4[0][0], a0, b0); DOT4(c4[0][1], a0, b1); DOT4(c4[0][2], a0, b2); DOT4(c4[0][3], a0, b3);
            DOT4(c4[1][0], a1, b0); DOT4(c4[1][1], a1, b1); DOT4(c4[1][2], a1, b2); DOT4(c4[1][3], a1, b3);
            DOT4(c4[2][0], a2, b0); DOT4(c4[2][1], a2, b1); DOT4(c4[2][2], a2, b2); DOT4(c4[2][3], a2, b3);
            DOT4(c4[3][0], a3, b0); DOT4(c4[3][1], a3, b1); DOT4(c4[3][2], a3, b2); DOT4(c4[3][3], a3, b3);
            #undef DOT4
        }

        // Online argmin update (per-thread j's visited in increasing order ->
        // strict < preserves first-occurrence semantics).
        #pragma unroll
        for (int jj = 0; jj < 4; jj++) {
            const int j = jt + jj * 16 + tx;
            if (j < jend) {
                const float tv = tn[j];
                #pragma unroll
                for (int i = 0; i < 4; i++) {
                    const float val = fmaf(-2.f, c4[i][jj], tv);
                    if (val < m[i]) { m[i] = val; am[i] = j; }
                }
            }
        }
    }

    __syncthreads();
    #pragma unroll
    for (int i = 0; i < 4; i++) {
        const int r = 4 * ty + i;
        redm[r * 16 + tx] = m[i];
        redi[r * 16 + tx] = am[i];
    }
    __syncthreads();
    if (tid < 64) {
        float best = redm[tid * 16];
        int   bi   = redi[tid * 16];
        #pragma unroll
        for (int t = 1; t < 16; t++) {
            const float v = redm[tid * 16 + t];
            const int  ii = redi[tid * 16 + t];
            if (v < best || (v == best && ii < bi)) { best = v; bi = ii; }
        }
        pmin[(size_t)(k0 + tid) * NC + cid] = best;
        pidx[(size_t)(k0 + tid) * NC + cid] = bi;
    }
}

// ---------------------------------------------------------------------------
// Combine chunk partials, add |a_k|^2, apply (ceil-floor)*(argmin != idx).
// ---------------------------------------------------------------------------
__global__ __launch_bounds__(256) void nn_finish(
    const float* __restrict__ MAP, int D,
    const int* __restrict__ gidx, int goff,
    const float* __restrict__ pmin, const int* __restrict__ pidx,
    int NC, int K, float* __restrict__ out, float inv_k)
{
    const int k = blockIdx.x * blockDim.x + threadIdx.x;
    float cnt = 0.f;
    if (k < K) {
        float best = __builtin_inff();
        int   bi   = 0x7fffffff;
        for (int c = 0; c < NC; c++) {
            const float v = pmin[(size_t)k * NC + c];
            const int  ii = pidx[(size_t)k * NC + c];
            if (v < best || (v == best && ii < bi)) { best = v; bi = ii; }
        }
        const int src = gidx[k * 2 + goff];
        const float* a = MAP + (size_t)src * D;
        float na = 0.f;
        for (int d = 0; d < D; d++) na = fmaf(a[d], a[d], na);
        const float d2 = na + best;
        const float v = sqrtf(fmaxf(d2, 0.f));
        const float mism = (bi != src) ? 1.f : 0.f;
        cnt = (ceilf(v) - floorf(v)) * mism;
    }
    #pragma unroll
    for (int o = 32; o > 0; o >>= 1) cnt += __shfl_down(cnt, o);
    if ((threadIdx.x & 63) == 0 && cnt != 0.f) atomicAdd(out, cnt * inv_k);
}

// ---------------------------------------------------------------------------
extern "C" void kernel_launch(void* const* d_in, const int* in_sizes, int n_in,
                              void* d_out, int out_size, void* d_ws, size_t ws_size,
                              hipStream_t stream)
{
    const float* xw    = (const float*)d_in[0];
    const float* yw    = (const float*)d_in[1];
    const float* fx_w1 = (const float*)d_in[2];
    const float* fx_b1 = (const float*)d_in[3];
    const float* fx_w2 = (const float*)d_in[4];
    const float* fx_b2 = (const float*)d_in[5];
    const float* gy_w1 = (const float*)d_in[6];
    const float* gy_b1 = (const float*)d_in[7];
    const float* gy_w2 = (const float*)d_in[8];
    const float* gy_b2 = (const float*)d_in[9];
    const int*   imap  = (const int*)d_in[10];
    float* out = (float*)d_out;
    float* ws  = (float*)d_ws;

    constexpr int N = 25000, K = 8000;
    constexpr int NC = 5;
    constexpr int CHUNK = (N + NC - 1) / NC;   // 5000

    float* xm      = ws;                         // N*120
    float* ym      = xm + (size_t)N * 120;       // N*100
    float* tn_y    = ym + (size_t)N * 100;       // N
    float* tn_x    = tn_y + N;                   // N
    float* pmin_fx = tn_x + N;                   // K*NC
    int*   pidx_fx = (int*)(pmin_fx + (size_t)K * NC);
    float* pmin_gy = (float*)(pidx_fx + (size_t)K * NC);
    int*   pidx_gy = (int*)(pmin_gy + (size_t)K * NC);

    hipMemsetAsync(d_out, 0, sizeof(float), stream);

    // Row norms of targets (needed by 1-NN kernels)
    norms_kernel<<<(2 * N * 64) / 256, 256, 0, stream>>>(yw, tn_y, xw, tn_x, N);

    // x_mapped = mlp_fx(x_weight); y_mapped = mlp_gy(y_weight)
    mlp_kernel<100, 120, true, false><<<256, 256, 0, stream>>>(
        xw, fx_w1, fx_b1, fx_w2, fx_b2, xm, nullptr, out, 0.f, N);
    mlp_kernel<120, 100, true, false><<<256, 256, 0, stream>>>(
        yw, gy_w1, gy_b1, gy_w2, gy_b2, ym, nullptr, out, 0.f, N);

    // cycle_fx = mean ||mlp_gy(x_mapped) - x_weight||; cycle_gy likewise
    mlp_kernel<120, 100, false, true><<<256, 256, 0, stream>>>(
        xm, gy_w1, gy_b1, gy_w2, gy_b2, nullptr, xw, out, 1.f / N, N);
    mlp_kernel<100, 120, false, true><<<256, 256, 0, stream>>>(
        ym, fx_w1, fx_b1, fx_w2, fx_b2, nullptr, yw, out, 1.f / N, N);

    // sup_x + sup_y
    sup_kernel<<<(K + 255) / 256, 256, 0, stream>>>(
        xm, ym, xw, yw, imap, K, out, 1.f / K);

    // 1-NN mismatch terms
    dim3 g1(K / 64, NC);
    nn_kernel<120, 124><<<g1, 256, 0, stream>>>(
        xm, imap, 0, yw, tn_y, N, pmin_fx, pidx_fx, NC, CHUNK);
    nn_kernel<100, 108><<<g1, 256, 0, stream>>>(
        ym, imap, 1, xw, tn_x, N, pmin_gy, pidx_gy, NC, CHUNK);

    nn_finish<<<(K + 255) / 256, 256, 0, stream>>>(
        xm, 120, imap, 0, pmin_fx, pidx_fx, NC, K, out, 1.f / K);
    nn_finish<<<(K + 255) / 256, 256, 0, stream>>>(
        ym, 100, imap, 1, pmin_gy, pidx_gy, NC, K, out, 1.f / K);
}

// Round 2
// 1636.952 us; speedup vs baseline: 1.8657x; 1.8657x over previous
//
#include <hip/hip_runtime.h>
#include <hip/hip_bf16.h>
#include <math.h>

#define HIDDEN 100

typedef __attribute__((ext_vector_type(8))) short bf16x8;
typedef __attribute__((ext_vector_type(4))) float f32x4;

__device__ inline unsigned short f2bf(float v) {
    union { float f; unsigned u; } x; x.f = v;
    unsigned r = x.u + 0x7fff + ((x.u >> 16) & 1);   // RNE
    return (unsigned short)(r >> 16);
}

// ---------------------------------------------------------------------------
// Fused 2-layer MLP: out = relu(X @ W1 + b1) @ W2 + b2 (unchanged from R1)
// ---------------------------------------------------------------------------
template<int DIN, int DOUT, bool STORE, bool NORM>
__global__ __launch_bounds__(256, 1) void mlp_kernel(
    const float* __restrict__ X,
    const float* __restrict__ W1, const float* __restrict__ B1,
    const float* __restrict__ W2, const float* __restrict__ B2,
    float* __restrict__ Y, const float* __restrict__ REF,
    float* __restrict__ out, float inv_n, int N)
{
    __shared__ float w1s[DIN * HIDDEN];
    __shared__ float w2s[HIDDEN * DOUT];
    __shared__ float xs[2][DIN];
    __shared__ float hs[2][HIDDEN];
    __shared__ float red[2][2];

    const int tid = threadIdx.x;
    for (int i = tid; i < DIN * HIDDEN; i += 256) w1s[i] = W1[i];
    for (int i = tid; i < HIDDEN * DOUT; i += 256) w2s[i] = W2[i];

    const int slot = tid >> 7;
    const int lane = tid & 127;
    const int wv   = lane >> 6;
    const int ln   = lane & 63;
    float acc = 0.f;

    __syncthreads();

    for (int row0 = blockIdx.x * 2; row0 < N; row0 += gridDim.x * 2) {
        const int row = row0 + slot;
        for (int i = lane; i < DIN; i += 128)
            xs[slot][i] = X[(size_t)row * DIN + i];
        __syncthreads();

        if (lane < HIDDEN) {
            float h = B1[lane];
            #pragma unroll 4
            for (int i = 0; i < DIN; i++)
                h = fmaf(xs[slot][i], w1s[i * HIDDEN + lane], h);
            hs[slot][lane] = fmaxf(h, 0.f);
        }
        __syncthreads();

        float nsum = 0.f;
        if (lane < DOUT) {
            float o = B2[lane];
            #pragma unroll 4
            for (int i = 0; i < HIDDEN; i++)
                o = fmaf(hs[slot][i], w2s[i * DOUT + lane], o);
            if (STORE) Y[(size_t)row * DOUT + lane] = o;
            if (NORM) {
                float d = o - REF[(size_t)row * DOUT + lane];
                nsum = d * d;
            }
        }
        if (NORM) {
            #pragma unroll
            for (int o = 32; o > 0; o >>= 1) nsum += __shfl_down(nsum, o);
            if (ln == 0) red[slot][wv] = nsum;
            __syncthreads();
            if (lane == 0) acc += sqrtf(red[slot][0] + red[slot][1]);
        }
        __syncthreads();
    }
    if (NORM && lane == 0) atomicAdd(out, acc * inv_n);
}

// ---------------------------------------------------------------------------
// Row squared-norms of the two target matrices (wave per row).
// ---------------------------------------------------------------------------
__global__ __launch_bounds__(256) void norms_kernel(
    const float* __restrict__ Y, float* __restrict__ tny,
    const float* __restrict__ X, float* __restrict__ tnx, int N)
{
    const int gw = (int)((blockIdx.x * blockDim.x + threadIdx.x) >> 6);
    const int ln = threadIdx.x & 63;
    float s = 0.f;
    if (gw < N) {
        const float* p = Y + (size_t)gw * 120;
        for (int d = ln; d < 120; d += 64) s = fmaf(p[d], p[d], s);
        #pragma unroll
        for (int o = 32; o > 0; o >>= 1) s += __shfl_down(s, o);
        if (ln == 0) tny[gw] = s;
    } else if (gw < 2 * N) {
        const int r = gw - N;
        const float* p = X + (size_t)r * 100;
        for (int d = ln; d < 100; d += 64) s = fmaf(p[d], p[d], s);
        #pragma unroll
        for (int o = 32; o > 0; o >>= 1) s += __shfl_down(s, o);
        if (ln == 0) tnx[r] = s;
    }
}

// ---------------------------------------------------------------------------
// Convert fp32 NxD (D<=128) to bf16 Nx128, zero padded.
// ---------------------------------------------------------------------------
__global__ __launch_bounds__(256) void conv_pad(
    const float* __restrict__ src, int D, unsigned short* __restrict__ dst, int N)
{
    const int t = blockIdx.x * 256 + threadIdx.x;
    if (t >= N * 128) return;
    const int r = t >> 7, c = t & 127;
    float v = 0.f;
    if (c < D) v = src[(size_t)r * D + c];
    dst[t] = f2bf(v);
}

// ---------------------------------------------------------------------------
// Gather rows of MAP by index column, convert to bf16 Kx128 zero padded.
// ---------------------------------------------------------------------------
__global__ __launch_bounds__(256) void gather_bf(
    const float* __restrict__ src, int D, const int* __restrict__ gidx, int goff,
    unsigned short* __restrict__ dst, int K)
{
    const int t = blockIdx.x * 256 + threadIdx.x;
    if (t >= K * 128) return;
    const int r = t >> 7, c = t & 127;
    float v = 0.f;
    if (c < D) v = src[(size_t)gidx[r * 2 + goff] * D + c];
    dst[t] = f2bf(v);
}

// ---------------------------------------------------------------------------
// sup_x + sup_y (unchanged).
// ---------------------------------------------------------------------------
__global__ __launch_bounds__(256) void sup_kernel(
    const float* __restrict__ xm, const float* __restrict__ ym,
    const float* __restrict__ xw, const float* __restrict__ yw,
    const int* __restrict__ im, int K, float* __restrict__ out, float inv_k)
{
    const int k = blockIdx.x * blockDim.x + threadIdx.x;
    float s = 0.f;
    if (k < K) {
        const int xi = im[2 * k], yi = im[2 * k + 1];
        const float* a = xm + (size_t)xi * 120;
        const float* b = yw + (size_t)yi * 120;
        float s1 = 0.f;
        for (int d = 0; d < 120; d++) { float df = a[d] - b[d]; s1 = fmaf(df, df, s1); }
        const float* c = ym + (size_t)yi * 100;
        const float* e = xw + (size_t)xi * 100;
        float s2 = 0.f;
        for (int d = 0; d < 100; d++) { float df = c[d] - e[d]; s2 = fmaf(df, df, s2); }
        s = sqrtf(s1) + sqrtf(s2);
    }
    #pragma unroll
    for (int o = 32; o > 0; o >>= 1) s += __shfl_down(s, o);
    if ((threadIdx.x & 63) == 0 && s != 0.f) atomicAdd(out, s * inv_k);
}

// ---------------------------------------------------------------------------
// MFMA 1-NN: A (Kx128 bf16, gathered mapped rows) vs T (Ntx128 bf16).
// Tracks min_j (tn[j] - 2 a.t_j) per A row over a j-chunk.
// mfma_f32_16x16x32_bf16; A/B frag: m=lane&15, k=(lane>>4)*8+j (16B contig);
// C/D: col=lane&15, row=(lane>>4)*4+reg. Each lane owns ONE j per tile ->
// 4-op argmin update per C element. B frags software-pipelined 1 tile ahead.
// ---------------------------------------------------------------------------
__global__ __launch_bounds__(256, 4) void nn_mfma(
    const unsigned short* __restrict__ A,
    const unsigned short* __restrict__ T,
    const float* __restrict__ tn, int Ntgt, int chunk,
    float* __restrict__ pmin, int* __restrict__ pidx, int NC)
{
    const int tid  = threadIdx.x;
    const int wv   = tid >> 6, ln = tid & 63;
    const int col  = ln & 15, quad = ln >> 4;
    const int arow = blockIdx.x * 64 + wv * 16 + col;
    const int cid  = blockIdx.y;
    const int jstart = cid * chunk;
    const int jend = min(jstart + chunk, Ntgt);

    // A fragments for the 4 k-steps, resident in VGPRs for the whole kernel.
    bf16x8 afrag[4];
    {
        const unsigned short* ab = A + (size_t)arow * 128 + quad * 8;
        #pragma unroll
        for (int s = 0; s < 4; s++)
            afrag[s] = *reinterpret_cast<const bf16x8*>(ab + s * 32);
    }

    float m[4]  = { __builtin_inff(), __builtin_inff(), __builtin_inff(), __builtin_inff() };
    int   am[4] = { 0x7fffffff, 0x7fffffff, 0x7fffffff, 0x7fffffff };

    // Prime the pipeline with the first B tile.
    bf16x8 bf[4];
    {
        const int jl = min(jstart + col, Ntgt - 1);
        const unsigned short* bb = T + (size_t)jl * 128 + quad * 8;
        #pragma unroll
        for (int s = 0; s < 4; s++)
            bf[s] = *reinterpret_cast<const bf16x8*>(bb + s * 32);
    }

    for (int j0 = jstart; j0 < jend; j0 += 16) {
        // Prefetch next B tile (clamped; garbage past jend is epilogue-guarded).
        bf16x8 nf[4];
        {
            const int jn = min(j0 + 16 + col, Ntgt - 1);
            const unsigned short* nb = T + (size_t)jn * 128 + quad * 8;
            #pragma unroll
            for (int s = 0; s < 4; s++)
                nf[s] = *reinterpret_cast<const bf16x8*>(nb + s * 32);
        }
        const int jr = j0 + col;
        const float tv = tn[min(jr, Ntgt - 1)];

        f32x4 acc = {0.f, 0.f, 0.f, 0.f};
        #pragma unroll
        for (int s = 0; s < 4; s++)
            acc = __builtin_amdgcn_mfma_f32_16x16x32_bf16(afrag[s], bf[s], acc, 0, 0, 0);

        if (jr < jend) {
            #pragma unroll
            for (int r = 0; r < 4; r++) {
                const float val = fmaf(-2.f, acc[r], tv);
                if (val < m[r]) { m[r] = val; am[r] = jr; }
            }
        }
        #pragma unroll
        for (int s = 0; s < 4; s++) bf[s] = nf[s];
    }

    // Cross-lane reduction: row (quad*4+r) is held by the 16 cols of this wave.
    __shared__ float rm[4][16][17];
    __shared__ int   ri[4][16][17];
    #pragma unroll
    for (int r = 0; r < 4; r++) {
        rm[wv][quad * 4 + r][col] = m[r];
        ri[wv][quad * 4 + r][col] = am[r];
    }
    __syncthreads();
    if (tid < 64) {
        const int w = tid >> 4, rr = tid & 15;
        float best = rm[w][rr][0];
        int   bi   = ri[w][rr][0];
        #pragma unroll
        for (int t = 1; t < 16; t++) {
            const float v = rm[w][rr][t];
            const int  ii = ri[w][rr][t];
            if (v < best || (v == best && ii < bi)) { best = v; bi = ii; }
        }
        const int krow = blockIdx.x * 64 + w * 16 + rr;
        pmin[(size_t)krow * NC + cid] = best;
        pidx[(size_t)krow * NC + cid] = bi;
    }
}

// ---------------------------------------------------------------------------
// Combine chunk partials, add |a_k|^2 (fp32), apply (ceil-floor)*(argmin!=idx).
// ---------------------------------------------------------------------------
__global__ __launch_bounds__(256) void nn_finish(
    const float* __restrict__ MAP, int D,
    const int* __restrict__ gidx, int goff,
    const float* __restrict__ pmin, const int* __restrict__ pidx,
    int NC, int K, float* __restrict__ out, float inv_k)
{
    const int k = blockIdx.x * blockDim.x + threadIdx.x;
    float cnt = 0.f;
    if (k < K) {
        float best = __builtin_inff();
        int   bi   = 0x7fffffff;
        for (int c = 0; c < NC; c++) {
            const float v = pmin[(size_t)k * NC + c];
            const int  ii = pidx[(size_t)k * NC + c];
            if (v < best || (v == best && ii < bi)) { best = v; bi = ii; }
        }
        const int src = gidx[k * 2 + goff];
        const float* a = MAP + (size_t)src * D;
        float na = 0.f;
        for (int d = 0; d < D; d++) na = fmaf(a[d], a[d], na);
        const float d2 = na + best;
        const float v = sqrtf(fmaxf(d2, 0.f));
        const float mism = (bi != src) ? 1.f : 0.f;
        cnt = (ceilf(v) - floorf(v)) * mism;
    }
    #pragma unroll
    for (int o = 32; o > 0; o >>= 1) cnt += __shfl_down(cnt, o);
    if ((threadIdx.x & 63) == 0 && cnt != 0.f) atomicAdd(out, cnt * inv_k);
}

// ---------------------------------------------------------------------------
extern "C" void kernel_launch(void* const* d_in, const int* in_sizes, int n_in,
                              void* d_out, int out_size, void* d_ws, size_t ws_size,
                              hipStream_t stream)
{
    const float* xw    = (const float*)d_in[0];
    const float* yw    = (const float*)d_in[1];
    const float* fx_w1 = (const float*)d_in[2];
    const float* fx_b1 = (const float*)d_in[3];
    const float* fx_w2 = (const float*)d_in[4];
    const float* fx_b2 = (const float*)d_in[5];
    const float* gy_w1 = (const float*)d_in[6];
    const float* gy_b1 = (const float*)d_in[7];
    const float* gy_w2 = (const float*)d_in[8];
    const float* gy_b2 = (const float*)d_in[9];
    const int*   imap  = (const int*)d_in[10];
    float* out = (float*)d_out;
    float* ws  = (float*)d_ws;

    constexpr int N = 25000, K = 8000;
    constexpr int NC = 10;
    constexpr int CHUNK = (N + NC - 1) / NC;   // 2500

    float* xm      = ws;                           // 3,000,000 f32
    float* ym      = xm + (size_t)N * 120;         // 2,500,000 f32
    float* tn_y    = ym + (size_t)N * 100;         // N
    float* tn_x    = tn_y + N;                     // N
    float* pmin_fx = tn_x + N;                     // K*NC
    int*   pidx_fx = (int*)(pmin_fx + (size_t)K * NC);
    float* pmin_gy = (float*)(pidx_fx + (size_t)K * NC);
    int*   pidx_gy = (int*)(pmin_gy + (size_t)K * NC);
    unsigned short* ybf = (unsigned short*)(pidx_gy + (size_t)K * NC); // N*128
    unsigned short* xbf = ybf + (size_t)N * 128;   // N*128
    unsigned short* axf = xbf + (size_t)N * 128;   // K*128
    unsigned short* ayf = axf + (size_t)K * 128;   // K*128

    hipMemsetAsync(d_out, 0, sizeof(float), stream);

    norms_kernel<<<(2 * N * 64) / 256, 256, 0, stream>>>(yw, tn_y, xw, tn_x, N);

    // bf16 target copies (depend only on inputs)
    conv_pad<<<(N * 128) / 256, 256, 0, stream>>>(yw, 120, ybf, N);
    conv_pad<<<(N * 128) / 256, 256, 0, stream>>>(xw, 100, xbf, N);

    // forward MLPs
    mlp_kernel<100, 120, true, false><<<256, 256, 0, stream>>>(
        xw, fx_w1, fx_b1, fx_w2, fx_b2, xm, nullptr, out, 0.f, N);
    mlp_kernel<120, 100, true, false><<<256, 256, 0, stream>>>(
        yw, gy_w1, gy_b1, gy_w2, gy_b2, ym, nullptr, out, 0.f, N);

    // cycle norms
    mlp_kernel<120, 100, false, true><<<256, 256, 0, stream>>>(
        xm, gy_w1, gy_b1, gy_w2, gy_b2, nullptr, xw, out, 1.f / N, N);
    mlp_kernel<100, 120, false, true><<<256, 256, 0, stream>>>(
        ym, fx_w1, fx_b1, fx_w2, fx_b2, nullptr, yw, out, 1.f / N, N);

    sup_kernel<<<(K + 255) / 256, 256, 0, stream>>>(
        xm, ym, xw, yw, imap, K, out, 1.f / K);

    // gathered A rows in bf16
    gather_bf<<<(K * 128) / 256, 256, 0, stream>>>(xm, 120, imap, 0, axf, K);
    gather_bf<<<(K * 128) / 256, 256, 0, stream>>>(ym, 100, imap, 1, ayf, K);

    // MFMA 1-NN
    dim3 g1(K / 64, NC);
    nn_mfma<<<g1, 256, 0, stream>>>(axf, ybf, tn_y, N, CHUNK, pmin_fx, pidx_fx, NC);
    nn_mfma<<<g1, 256, 0, stream>>>(ayf, xbf, tn_x, N, CHUNK, pmin_gy, pidx_gy, NC);

    nn_finish<<<(K + 255) / 256, 256, 0, stream>>>(
        xm, 120, imap, 0, pmin_fx, pidx_fx, NC, K, out, 1.f / K);
    nn_finish<<<(K + 255) / 256, 256, 0, stream>>>(
        ym, 100, imap, 1, pmin_gy, pidx_gy, NC, K, out, 1.f / K);
}

// Round 3
// 631.781 us; speedup vs baseline: 4.8340x; 2.5910x over previous
//
#include <hip/hip_runtime.h>
#include <hip/hip_bf16.h>
#include <math.h>

#define HIDDEN 100

typedef __attribute__((ext_vector_type(8))) short bf16x8;
typedef __attribute__((ext_vector_type(4))) float f32x4;

__device__ inline unsigned short f2bf(float v) {
    union { float f; unsigned u; } x; x.f = v;
    unsigned r = x.u + 0x7fff + ((x.u >> 16) & 1);   // RNE
    return (unsigned short)(r >> 16);
}

constexpr int NPTS  = 25000;
constexpr int KPAIR = 8000;
constexpr int NC    = 16;
constexpr int CHUNK = 1568;   // multiple of 32, 16*1568 = 25088 >= 25000

// ---------------------------------------------------------------------------
// Fused 2-layer MLP, 8 rows/tile, thread = (row rr=tid>>5, cols c4=(tid&31)*4).
// Weights in LDS (W1 padded to HP=104 cols for float4). 4 independent FMA
// chains per thread; W reads broadcast across the 8 rows.
// ---------------------------------------------------------------------------
template<int DIN, int DOUT, bool STORE, bool NORM>
__global__ __launch_bounds__(256, 1) void mlp_kernel(
    const float* __restrict__ X,
    const float* __restrict__ W1, const float* __restrict__ B1,
    const float* __restrict__ W2, const float* __restrict__ B2,
    float* __restrict__ Y, const float* __restrict__ REF,
    float* __restrict__ out, float inv_n, int N)
{
    constexpr int HP = 104;
    __shared__ float w1s[DIN * HP];
    __shared__ float w2s[HIDDEN * DOUT];
    __shared__ float xs[8][DIN];
    __shared__ float hs[8][HP];
    __shared__ float bred[8];

    const int tid = threadIdx.x;
    for (int idx = tid; idx < DIN * HP; idx += 256) {
        const int i = idx / HP, c = idx - i * HP;
        w1s[idx] = (c < HIDDEN) ? W1[i * HIDDEN + c] : 0.f;
    }
    for (int idx = tid; idx < HIDDEN * DOUT; idx += 256) w2s[idx] = W2[idx];

    const int rr = tid >> 5;
    const int cg = tid & 31;
    const int c4 = cg * 4;

    float b1v0 = 0.f, b1v1 = 0.f, b1v2 = 0.f, b1v3 = 0.f;
    if (c4 < HP) {
        b1v0 = (c4 + 0 < HIDDEN) ? B1[c4 + 0] : 0.f;
        b1v1 = (c4 + 1 < HIDDEN) ? B1[c4 + 1] : 0.f;
        b1v2 = (c4 + 2 < HIDDEN) ? B1[c4 + 2] : 0.f;
        b1v3 = (c4 + 3 < HIDDEN) ? B1[c4 + 3] : 0.f;
    }
    float4 b2v = {0.f, 0.f, 0.f, 0.f};
    if (c4 < DOUT) b2v = *reinterpret_cast<const float4*>(B2 + c4);

    float nacc = 0.f;
    __syncthreads();

    for (int row0 = blockIdx.x * 8; row0 < N; row0 += gridDim.x * 8) {
        for (int idx = tid; idx < 8 * DIN; idx += 256) {
            const int r = idx / DIN, d = idx - r * DIN;
            xs[r][d] = X[(size_t)(row0 + r) * DIN + d];
        }
        __syncthreads();

        if (c4 < HP) {
            float h0 = b1v0, h1 = b1v1, h2 = b1v2, h3 = b1v3;
            #pragma unroll 4
            for (int i = 0; i < DIN; i++) {
                const float xv = xs[rr][i];
                const float4 w = *reinterpret_cast<const float4*>(&w1s[i * HP + c4]);
                h0 = fmaf(xv, w.x, h0); h1 = fmaf(xv, w.y, h1);
                h2 = fmaf(xv, w.z, h2); h3 = fmaf(xv, w.w, h3);
            }
            float4 hv = {fmaxf(h0, 0.f), fmaxf(h1, 0.f), fmaxf(h2, 0.f), fmaxf(h3, 0.f)};
            *reinterpret_cast<float4*>(&hs[rr][c4]) = hv;
        }
        __syncthreads();

        float s = 0.f;
        if (c4 < DOUT) {
            float o0 = b2v.x, o1 = b2v.y, o2 = b2v.z, o3 = b2v.w;
            #pragma unroll 4
            for (int i = 0; i < HIDDEN; i++) {
                const float hv = hs[rr][i];
                const float4 w = *reinterpret_cast<const float4*>(&w2s[i * DOUT + c4]);
                o0 = fmaf(hv, w.x, o0); o1 = fmaf(hv, w.y, o1);
                o2 = fmaf(hv, w.z, o2); o3 = fmaf(hv, w.w, o3);
            }
            if (STORE) {
                float4 ov = {o0, o1, o2, o3};
                *reinterpret_cast<float4*>(&Y[(size_t)(row0 + rr) * DOUT + c4]) = ov;
            }
            if (NORM) {
                const float4 rv = *reinterpret_cast<const float4*>(&REF[(size_t)(row0 + rr) * DOUT + c4]);
                const float d0 = o0 - rv.x, d1 = o1 - rv.y, d2 = o2 - rv.z, d3 = o3 - rv.w;
                s = fmaf(d0, d0, fmaf(d1, d1, fmaf(d2, d2, d3 * d3)));
            }
        }
        if (NORM) {
            #pragma unroll
            for (int o = 16; o >= 1; o >>= 1) s += __shfl_down(s, o, 32);
            if (cg == 0) nacc += sqrtf(s);
        }
        __syncthreads();
    }
    if (NORM) {
        if (cg == 0) bred[rr] = nacc;
        __syncthreads();
        if (tid == 0) {
            float t = 0.f;
            #pragma unroll
            for (int r = 0; r < 8; r++) t += bred[r];
            atomicAdd(out, t * inv_n);
        }
    }
}

// ---------------------------------------------------------------------------
// Row squared-norms of the two target matrices (wave per row).
// ---------------------------------------------------------------------------
__global__ __launch_bounds__(256) void norms_kernel(
    const float* __restrict__ Y, float* __restrict__ tny,
    const float* __restrict__ X, float* __restrict__ tnx, int N)
{
    const int gw = (int)((blockIdx.x * blockDim.x + threadIdx.x) >> 6);
    const int ln = threadIdx.x & 63;
    float s = 0.f;
    if (gw < N) {
        const float* p = Y + (size_t)gw * 120;
        for (int d = ln; d < 120; d += 64) s = fmaf(p[d], p[d], s);
        #pragma unroll
        for (int o = 32; o > 0; o >>= 1) s += __shfl_down(s, o);
        if (ln == 0) tny[gw] = s;
    } else if (gw < 2 * N) {
        const int r = gw - N;
        const float* p = X + (size_t)r * 100;
        for (int d = ln; d < 100; d += 64) s = fmaf(p[d], p[d], s);
        #pragma unroll
        for (int o = 32; o > 0; o >>= 1) s += __shfl_down(s, o);
        if (ln == 0) tnx[r] = s;
    }
}

// ---------------------------------------------------------------------------
// fp32 NxD -> bf16 Nx128 zero-padded; col 127 carries tn[row] (|t|^2).
// ---------------------------------------------------------------------------
__global__ __launch_bounds__(256) void conv_pad(
    const float* __restrict__ src, int D, const float* __restrict__ tn,
    unsigned short* __restrict__ dst, int N)
{
    const int t = blockIdx.x * 256 + threadIdx.x;
    if (t >= N * 128) return;
    const int r = t >> 7, c = t & 127;
    float v = 0.f;
    if (c < D) v = src[(size_t)r * D + c];
    else if (c == 127) v = tn[r];
    dst[t] = f2bf(v);
}

// ---------------------------------------------------------------------------
// Gather rows of MAP, scale by -2, bf16 Kx128 zero-padded; col 127 = 1.0.
// ---------------------------------------------------------------------------
__global__ __launch_bounds__(256) void gather_bf(
    const float* __restrict__ src, int D, const int* __restrict__ gidx, int goff,
    unsigned short* __restrict__ dst, int K)
{
    const int t = blockIdx.x * 256 + threadIdx.x;
    if (t >= K * 128) return;
    const int r = t >> 7, c = t & 127;
    float v = 0.f;
    if (c < D) v = -2.f * src[(size_t)gidx[r * 2 + goff] * D + c];
    else if (c == 127) v = 1.f;
    dst[t] = f2bf(v);
}

// ---------------------------------------------------------------------------
// sup_x + sup_y: wave per pair, coalesced row loads, per-block atomic.
// ---------------------------------------------------------------------------
__global__ __launch_bounds__(256) void sup_kernel(
    const float* __restrict__ xm, const float* __restrict__ ym,
    const float* __restrict__ xw, const float* __restrict__ yw,
    const int* __restrict__ im, int K, float* __restrict__ out, float inv_k)
{
    const int gw = (int)((blockIdx.x * 256 + threadIdx.x) >> 6);
    const int ln = threadIdx.x & 63;
    const int wv = threadIdx.x >> 6;
    float cnt = 0.f;
    if (gw < K) {
        const int xi = im[2 * gw], yi = im[2 * gw + 1];
        const float* a = xm + (size_t)xi * 120;
        const float* b = yw + (size_t)yi * 120;
        float s1 = 0.f;
        for (int d = ln; d < 120; d += 64) { const float df = a[d] - b[d]; s1 = fmaf(df, df, s1); }
        const float* c = ym + (size_t)yi * 100;
        const float* e = xw + (size_t)xi * 100;
        float s2 = 0.f;
        for (int d = ln; d < 100; d += 64) { const float df = c[d] - e[d]; s2 = fmaf(df, df, s2); }
        #pragma unroll
        for (int o = 32; o > 0; o >>= 1) { s1 += __shfl_down(s1, o); s2 += __shfl_down(s2, o); }
        if (ln == 0) cnt = sqrtf(s1) + sqrtf(s2);
    }
    __shared__ float wsum[4];
    if (ln == 0) wsum[wv] = cnt;
    __syncthreads();
    if (threadIdx.x == 0) {
        const float t = wsum[0] + wsum[1] + wsum[2] + wsum[3];
        if (t != 0.f) atomicAdd(out, t * inv_k);
    }
}

// ---------------------------------------------------------------------------
// MFMA 1-NN v3. Block = 256 A rows (wave w: rows w*64..w*64+63, 4 rowtiles).
// B tiles (32 rows x 128) double-buffered in LDS (stride 136 shorts), shared
// by all 4 waves. A col127=1, T col127=tn => MFMA acc = tn[j] - 2 a.t_j.
// Argmin packed: low 11 mantissa bits replaced by j>>4 (wave-uniform), then
// v_min_f32. Rows >= jend staged as zeros + col127=1e30 (never win).
// ---------------------------------------------------------------------------
__global__ __launch_bounds__(256, 3) void nn_mfma(
    const unsigned short* __restrict__ A,
    const unsigned short* __restrict__ T,
    int Ntgt, int K,
    float* __restrict__ pmin, int* __restrict__ pidx)
{
    constexpr int BS = 136;   // LDS row stride (shorts); pad for bank spread
    __shared__ unsigned short bsm[2][32 * BS];
    __shared__ float rm[4][64][17];

    const int tid = threadIdx.x;
    const int wv = tid >> 6, ln = tid & 63;
    const int col = ln & 15, quad = ln >> 4;
    const int k0 = blockIdx.x * 256;
    const int jstart = blockIdx.y * CHUNK;
    const int jend = min(jstart + CHUNK, Ntgt);
    const int nt = (jend - jstart + 31) >> 5;

    // A fragments: 4 rowtiles x 4 k-steps, VGPR-resident.
    bf16x8 afrag[4][4];
    #pragma unroll
    for (int t = 0; t < 4; t++) {
        const int ar = min(k0 + wv * 64 + t * 16 + col, K - 1);
        const unsigned short* ab = A + (size_t)ar * 128 + quad * 8;
        #pragma unroll
        for (int s = 0; s < 4; s++)
            afrag[t][s] = *reinterpret_cast<const bf16x8*>(ab + s * 32);
    }

    float m[4][4];
    #pragma unroll
    for (int t = 0; t < 4; t++)
        #pragma unroll
        for (int r = 0; r < 4; r++) m[t][r] = __builtin_inff();

    const unsigned bigw = ((unsigned)f2bf(1e30f)) << 16;   // col127 slot of uint4.w

    // ---- stage tile 0 ----
    {
        #pragma unroll
        for (int half = 0; half < 2; half++) {
            const int c = tid + half * 256;
            const int r = c >> 4, off = c & 15;
            const int j = jstart + r;
            uint4 v;
            if (j < jend) v = reinterpret_cast<const uint4*>(T + (size_t)j * 128)[off];
            else { v.x = 0; v.y = 0; v.z = 0; v.w = (off == 15) ? bigw : 0u; }
            *reinterpret_cast<uint4*>(&bsm[0][r * BS + off * 8]) = v;
        }
    }
    __syncthreads();

    for (int ti = 0; ti < nt; ti++) {
        const int cur = ti & 1;
        const bool have = (ti + 1 < nt);
        uint4 v0, v1;
        if (have) {
            #pragma unroll
            for (int half = 0; half < 2; half++) {
                const int c = tid + half * 256;
                const int r = c >> 4, off = c & 15;
                const int j = jstart + (ti + 1) * 32 + r;
                uint4 v;
                if (j < jend) v = reinterpret_cast<const uint4*>(T + (size_t)j * 128)[off];
                else { v.x = 0; v.y = 0; v.z = 0; v.w = (off == 15) ? bigw : 0u; }
                if (half == 0) v0 = v; else v1 = v;
            }
        }

        const unsigned short* buf = bsm[cur];
        const unsigned lowbase = (unsigned)((jstart + ti * 32) >> 4);
        #pragma unroll
        for (int sub = 0; sub < 2; sub++) {
            bf16x8 bfr[4];
            const unsigned short* bb = buf + (sub * 16 + col) * BS + quad * 8;
            #pragma unroll
            for (int s = 0; s < 4; s++)
                bfr[s] = *reinterpret_cast<const bf16x8*>(bb + s * 32);
            const unsigned low = lowbase + sub;
            #pragma unroll
            for (int t = 0; t < 4; t++) {
                f32x4 acc = {0.f, 0.f, 0.f, 0.f};
                #pragma unroll
                for (int s = 0; s < 4; s++)
                    acc = __builtin_amdgcn_mfma_f32_16x16x32_bf16(afrag[t][s], bfr[s], acc, 0, 0, 0);
                #pragma unroll
                for (int r = 0; r < 4; r++) {
                    const unsigned u = (__float_as_uint(acc[r]) & 0xFFFFF800u) | low;
                    m[t][r] = fminf(m[t][r], __uint_as_float(u));
                }
            }
        }

        if (have) {
            {
                const int c = tid, r = c >> 4, off = c & 15;
                *reinterpret_cast<uint4*>(&bsm[cur ^ 1][r * BS + off * 8]) = v0;
            }
            {
                const int c = tid + 256, r = c >> 4, off = c & 15;
                *reinterpret_cast<uint4*>(&bsm[cur ^ 1][r * BS + off * 8]) = v1;
            }
        }
        __syncthreads();
    }

    // ---- reduction: per A-row min over the 16 cols ----
    #pragma unroll
    for (int t = 0; t < 4; t++)
        #pragma unroll
        for (int r = 0; r < 4; r++)
            rm[wv][t * 16 + quad * 4 + r][col] = m[t][r];
    __syncthreads();

    const int k = k0 + tid;
    if (k < K) {
        const int w = tid >> 6, rr = tid & 63;
        float best = rm[w][rr][0];
        int bc = 0;
        #pragma unroll
        for (int c = 1; c < 16; c++) {
            const float v = rm[w][rr][c];
            if (v < best) { best = v; bc = c; }
        }
        const int j = (int)(((__float_as_uint(best) & 0x7FFu) << 4) | (unsigned)bc);
        pmin[(size_t)k * NC + blockIdx.y] = best;
        pidx[(size_t)k * NC + blockIdx.y] = j;
    }
}

// ---------------------------------------------------------------------------
// Finish both mismatch terms: wave per (dir, k). Cross-chunk argmin by packed
// value (ties -> smaller j), then EXACT fp32 distance recompute for the
// selected index, then (ceil-floor)*(argmin != idx). Per-block atomic.
// ---------------------------------------------------------------------------
__global__ __launch_bounds__(256) void finish2(
    const float* __restrict__ xm, const float* __restrict__ ym,
    const float* __restrict__ xw, const float* __restrict__ yw,
    const int* __restrict__ im,
    const float* __restrict__ pmin_fx, const int* __restrict__ pidx_fx,
    const float* __restrict__ pmin_gy, const int* __restrict__ pidx_gy,
    int K, float* __restrict__ out, float inv_k)
{
    const int gw = (int)((blockIdx.x * 256 + threadIdx.x) >> 6);
    const int ln = threadIdx.x & 63;
    const int wvi = threadIdx.x >> 6;
    float cnt = 0.f;
    if (gw < 2 * K) {
        const int dir = (gw >= K) ? 1 : 0;
        const int kk = dir ? gw - K : gw;
        const float* pm = dir ? pmin_gy : pmin_fx;
        const int*   pi = dir ? pidx_gy : pidx_fx;

        float v = (ln < NC) ? pm[(size_t)kk * NC + ln] : __builtin_inff();
        int  ii = (ln < NC) ? pi[(size_t)kk * NC + ln] : 0x7fffffff;
        #pragma unroll
        for (int o = 8; o >= 1; o >>= 1) {
            const float ov = __shfl_down(v, o);
            const int   oi = __shfl_down(ii, o);
            if (ov < v || (ov == v && oi < ii)) { v = ov; ii = oi; }
        }
        const int bi = __shfl(ii, 0);
        const int src = im[2 * kk + dir];
        const float* a = dir ? (ym + (size_t)src * 100) : (xm + (size_t)src * 120);
        const float* t = dir ? (xw + (size_t)bi * 100) : (yw + (size_t)bi * 120);
        const int D = dir ? 100 : 120;
        float s = 0.f;
        for (int d = ln; d < D; d += 64) { const float df = a[d] - t[d]; s = fmaf(df, df, s); }
        #pragma unroll
        for (int o = 32; o > 0; o >>= 1) s += __shfl_down(s, o);
        if (ln == 0) {
            const float dist = sqrtf(s);
            cnt = (ceilf(dist) - floorf(dist)) * ((bi != src) ? 1.f : 0.f);
        }
    }
    __shared__ float wsum[4];
    if (ln == 0) wsum[wvi] = cnt;
    __syncthreads();
    if (threadIdx.x == 0) {
        const float t = wsum[0] + wsum[1] + wsum[2] + wsum[3];
        if (t != 0.f) atomicAdd(out, t * inv_k);
    }
}

// ---------------------------------------------------------------------------
extern "C" void kernel_launch(void* const* d_in, const int* in_sizes, int n_in,
                              void* d_out, int out_size, void* d_ws, size_t ws_size,
                              hipStream_t stream)
{
    const float* xw    = (const float*)d_in[0];
    const float* yw    = (const float*)d_in[1];
    const float* fx_w1 = (const float*)d_in[2];
    const float* fx_b1 = (const float*)d_in[3];
    const float* fx_w2 = (const float*)d_in[4];
    const float* fx_b2 = (const float*)d_in[5];
    const float* gy_w1 = (const float*)d_in[6];
    const float* gy_b1 = (const float*)d_in[7];
    const float* gy_w2 = (const float*)d_in[8];
    const float* gy_b2 = (const float*)d_in[9];
    const int*   imap  = (const int*)d_in[10];
    float* out = (float*)d_out;
    float* ws  = (float*)d_ws;

    constexpr int N = NPTS, K = KPAIR;

    float* xm      = ws;                           // N*120
    float* ym      = xm + (size_t)N * 120;         // N*100
    float* tn_y    = ym + (size_t)N * 100;         // N
    float* tn_x    = tn_y + N;                     // N
    float* pmin_fx = tn_x + N;                     // K*NC
    int*   pidx_fx = (int*)(pmin_fx + (size_t)K * NC);
    float* pmin_gy = (float*)(pidx_fx + (size_t)K * NC);
    int*   pidx_gy = (int*)(pmin_gy + (size_t)K * NC);
    unsigned short* ybf = (unsigned short*)(pidx_gy + (size_t)K * NC); // N*128
    unsigned short* xbf = ybf + (size_t)N * 128;
    unsigned short* axf = xbf + (size_t)N * 128;   // K*128
    unsigned short* ayf = axf + (size_t)K * 128;

    hipMemsetAsync(d_out, 0, sizeof(float), stream);

    norms_kernel<<<(2 * N * 64) / 256, 256, 0, stream>>>(yw, tn_y, xw, tn_x, N);

    // bf16 target panels (col 127 = |t|^2)
    conv_pad<<<(N * 128) / 256, 256, 0, stream>>>(yw, 120, tn_y, ybf, N);
    conv_pad<<<(N * 128) / 256, 256, 0, stream>>>(xw, 100, tn_x, xbf, N);

    // forward MLPs
    mlp_kernel<100, 120, true, false><<<256, 256, 0, stream>>>(
        xw, fx_w1, fx_b1, fx_w2, fx_b2, xm, nullptr, out, 0.f, N);
    mlp_kernel<120, 100, true, false><<<256, 256, 0, stream>>>(
        yw, gy_w1, gy_b1, gy_w2, gy_b2, ym, nullptr, out, 0.f, N);

    // cycle norms
    mlp_kernel<120, 100, false, true><<<256, 256, 0, stream>>>(
        xm, gy_w1, gy_b1, gy_w2, gy_b2, nullptr, xw, out, 1.f / N, N);
    mlp_kernel<100, 120, false, true><<<256, 256, 0, stream>>>(
        ym, fx_w1, fx_b1, fx_w2, fx_b2, nullptr, yw, out, 1.f / N, N);

    sup_kernel<<<(K * 64) / 256, 256, 0, stream>>>(
        xm, ym, xw, yw, imap, K, out, 1.f / K);

    // gathered query panels (scaled -2, col 127 = 1)
    gather_bf<<<(K * 128) / 256, 256, 0, stream>>>(xm, 120, imap, 0, axf, K);
    gather_bf<<<(K * 128) / 256, 256, 0, stream>>>(ym, 100, imap, 1, ayf, K);

    // MFMA 1-NN
    dim3 g1((K + 255) / 256, NC);
    nn_mfma<<<g1, 256, 0, stream>>>(axf, ybf, N, K, pmin_fx, pidx_fx);
    nn_mfma<<<g1, 256, 0, stream>>>(ayf, xbf, N, K, pmin_gy, pidx_gy);

    finish2<<<(2 * K * 64) / 256, 256, 0, stream>>>(
        xm, ym, xw, yw, imap, pmin_fx, pidx_fx, pmin_gy, pidx_gy, K, out, 1.f / K);
}

// Round 4
// 334.507 us; speedup vs baseline: 9.1299x; 1.8887x over previous
//
#include <hip/hip_runtime.h>
#include <hip/hip_bf16.h>
#include <math.h>

#define HIDDEN 100

typedef __attribute__((ext_vector_type(8))) short bf16x8;
typedef __attribute__((ext_vector_type(4))) float f32x4;

__device__ inline unsigned short f2bf(float v) {
    union { float f; unsigned u; } x; x.f = v;
    unsigned r = x.u + 0x7fff + ((x.u >> 16) & 1);   // RNE
    return (unsigned short)(r >> 16);
}

constexpr int NPTS  = 25000;
constexpr int KPAIR = 8000;
constexpr int NC    = 16;
constexpr int CHUNK = 1568;   // multiple of 32, 16*1568 = 25088 >= 25000
constexpr int HS    = 136;    // LDS H-slab stride (shorts)

// ---------------------------------------------------------------------------
// Weight prep: fp32 W (DKxDN) -> fragment-ordered bf16 panels, zero-padded to
// k<128, n<NT*16. Frag f=kt*NT+nt: lane ln holds B[k0+quad*8+j][n0+(ln&15)].
// Zero padding on the B side kills any garbage in A-side padding columns.
// blocks: [0,28) fx_w1, [28,60) fx_w2, [60,88) gy_w1, [88,116) gy_w2.
// ---------------------------------------------------------------------------
__global__ __launch_bounds__(64) void w_prep(
    const float* __restrict__ W1, unsigned short* __restrict__ P1,
    const float* __restrict__ W2, unsigned short* __restrict__ P2,
    const float* __restrict__ W3, unsigned short* __restrict__ P3,
    const float* __restrict__ W4, unsigned short* __restrict__ P4)
{
    int b = blockIdx.x;
    const float* W; unsigned short* P; int DK, DN, NT;
    if (b < 28)      {          W = W1; P = P1; DK = 100; DN = 100; NT = 7; }
    else if (b < 60) { b -= 28; W = W2; P = P2; DK = 100; DN = 120; NT = 8; }
    else if (b < 88) { b -= 60; W = W3; P = P3; DK = 120; DN = 100; NT = 7; }
    else             { b -= 88; W = W4; P = P4; DK = 100; DN = 100; NT = 7; }
    const int kt = b / NT, nt = b - kt * NT;
    const int ln = threadIdx.x;
    const int n  = nt * 16 + (ln & 15);
    const int k0 = kt * 32 + (ln >> 4) * 8;
    unsigned short* dst = P + ((size_t)(kt * NT + nt) * 64 + ln) * 8;
    #pragma unroll
    for (int j = 0; j < 8; j++) {
        const int k = k0 + j;
        const float f = (k < DK && n < DN) ? W[k * DN + n] : 0.f;
        dst[j] = f2bf(f);
    }
}

// ---------------------------------------------------------------------------
// MFMA stage helpers. A-frag: m=lane&15, k=quad*8+j. C: col=lane&15,
// row=quad*4+reg (HW-verified layouts from nn_mfma, absmax 0.0 in R2/R3).
// ---------------------------------------------------------------------------
template<int NT>
__device__ inline void run_stage(const bf16x8 af[4], const unsigned short* __restrict__ WP,
                                 int ln, f32x4 acc[NT])
{
    #pragma unroll
    for (int nt = 0; nt < NT; nt++) acc[nt] = (f32x4){0.f, 0.f, 0.f, 0.f};
    #pragma unroll
    for (int kt = 0; kt < 4; kt++) {
        #pragma unroll
        for (int nt = 0; nt < NT; nt++) {
            const bf16x8 wf = *reinterpret_cast<const bf16x8*>(WP + ((size_t)(kt * NT + nt) * 64 + ln) * 8);
            acc[nt] = __builtin_amdgcn_mfma_f32_16x16x32_bf16(af[kt], wf, acc[nt], 0, 0, 0);
        }
    }
}

// bias + optional relu, pack bf16 into wave-private LDS slab (row-major, HS stride)
template<int NT, int DN, bool RELU>
__device__ inline void pack_h(const f32x4 acc[NT], const float* __restrict__ B,
                              unsigned short* __restrict__ Hs, int col, int quad)
{
    #pragma unroll
    for (int nt = 0; nt < NT; nt++) {
        const int n = nt * 16 + col;
        const float b = (n < DN) ? B[n] : 0.f;
        #pragma unroll
        for (int r = 0; r < 4; r++) {
            float v = acc[nt][r] + b;
            if (RELU) v = fmaxf(v, 0.f);
            Hs[(quad * 4 + r) * HS + n] = f2bf(v);
        }
    }
}

// bias, store fp32 to global Y, pack bf16 into LDS slab (no relu)
template<int NT, int DN>
__device__ inline void store_pack(const f32x4 acc[NT], const float* __restrict__ B,
                                  float* __restrict__ Y, unsigned short* __restrict__ Hs,
                                  int rowbase, int col, int quad, int N)
{
    #pragma unroll
    for (int nt = 0; nt < NT; nt++) {
        const int n = nt * 16 + col;
        const float b = (n < DN) ? B[n] : 0.f;
        #pragma unroll
        for (int r = 0; r < 4; r++) {
            const float v = acc[nt][r] + b;
            const int row = rowbase + quad * 4 + r;
            if (n < DN && row < N) Y[(size_t)row * DN + n] = v;
            Hs[(quad * 4 + r) * HS + n] = f2bf(v);
        }
    }
}

__device__ inline void load_haf(const unsigned short* __restrict__ Hs, int col, int quad,
                                bf16x8 af[4])
{
    const unsigned short* p = Hs + col * HS + quad * 8;
    #pragma unroll
    for (int kt = 0; kt < 4; kt++)
        af[kt] = *reinterpret_cast<const bf16x8*>(p + kt * 32);
}

// bias, compare vs REF, per-row sum of squares; cross-lane reduce over the 16
// C-columns (xor 1,2,4,8 stays inside the 16-lane group). Returns per-lane
// contribution (nonzero only at col==0): sum over 4 rows of sqrt(rowsum).
template<int NT, int DN>
__device__ inline float norm_stage(const f32x4 acc[NT], const float* __restrict__ B,
                                   const float* __restrict__ REF,
                                   int rowbase, int col, int quad, int N)
{
    float ra[4] = {0.f, 0.f, 0.f, 0.f};
    #pragma unroll
    for (int nt = 0; nt < NT; nt++) {
        const int n = nt * 16 + col;
        if (n < DN) {
            const float b = B[n];
            #pragma unroll
            for (int r = 0; r < 4; r++) {
                const int row = rowbase + quad * 4 + r;
                if (row < N) {
                    const float d = acc[nt][r] + b - REF[(size_t)row * DN + n];
                    ra[r] = fmaf(d, d, ra[r]);
                }
            }
        }
    }
    #pragma unroll
    for (int o = 1; o < 16; o <<= 1) {
        #pragma unroll
        for (int r = 0; r < 4; r++) ra[r] += __shfl_xor(ra[r], o);
    }
    float s = 0.f;
    if (col == 0) {
        #pragma unroll
        for (int r = 0; r < 4; r++)
            if (rowbase + quad * 4 + r < N) s += sqrtf(ra[r]);
    }
    return s;
}

// ---------------------------------------------------------------------------
// Fused 4-stage MLP chain per direction (bf16 MFMA, fp32 accum):
//   in -> W1(DIN->100) relu -> W2(100->DMID) [store fp32 Y=mapped]
//      -> W3(DMID->100) relu -> W4(100->DIN) -> mean row ||.-REF||  (atomic)
// Block = 64 rows (4 waves x 16). Inter-stage data in wave-private LDS slab
// (no __syncthreads between stages). Weight frags from L1/L2-resident panels.
// ---------------------------------------------------------------------------
template<int DIN, int DMID, int NT2, int NTF>
__global__ __launch_bounds__(256) void mlp_fused(
    const unsigned short* __restrict__ Xbf,   // N x 128 bf16 (padding killed by W panels)
    const float* __restrict__ XREF,           // N x DIN fp32 original input
    const unsigned short* __restrict__ WP1, const float* __restrict__ B1,
    const unsigned short* __restrict__ WP2, const float* __restrict__ B2,
    const unsigned short* __restrict__ WP3, const float* __restrict__ B3,
    const unsigned short* __restrict__ WP4, const float* __restrict__ B4,
    float* __restrict__ Y,                    // N x DMID mapped output
    float* __restrict__ out, float inv_n, int N)
{
    __shared__ unsigned short H[4][16 * HS];
    __shared__ float bred[16];

    const int tid = threadIdx.x;
    const int wv = tid >> 6, ln = tid & 63;
    const int col = ln & 15, quad = ln >> 4;
    const int rowbase = blockIdx.x * 64 + wv * 16;

    // zero wave slab once (cols never written must be finite-zero)
    {
        unsigned* Hz = reinterpret_cast<unsigned*>(H[wv]);
        for (int i = ln; i < 16 * HS / 2; i += 64) Hz[i] = 0u;
    }

    // stage 1 A-frags from global
    bf16x8 af[4];
    {
        const int r = min(rowbase + col, N - 1);
        const unsigned short* ap = Xbf + (size_t)r * 128 + quad * 8;
        #pragma unroll
        for (int kt = 0; kt < 4; kt++) af[kt] = *reinterpret_cast<const bf16x8*>(ap + kt * 32);
    }

    f32x4 accA[7];
    run_stage<7>(af, WP1, ln, accA);
    pack_h<7, HIDDEN, true>(accA, B1, H[wv], col, quad);
    load_haf(H[wv], col, quad, af);

    f32x4 accB[NT2];
    run_stage<NT2>(af, WP2, ln, accB);
    store_pack<NT2, DMID>(accB, B2, Y, H[wv], rowbase, col, quad, N);
    load_haf(H[wv], col, quad, af);

    run_stage<7>(af, WP3, ln, accA);
    pack_h<7, HIDDEN, true>(accA, B3, H[wv], col, quad);
    load_haf(H[wv], col, quad, af);

    f32x4 accC[NTF];
    run_stage<NTF>(af, WP4, ln, accC);
    const float s = norm_stage<NTF, DIN>(accC, B4, XREF, rowbase, col, quad, N);

    if (col == 0) bred[wv * 4 + quad] = s;
    __syncthreads();
    if (tid == 0) {
        float t = 0.f;
        #pragma unroll
        for (int i = 0; i < 16; i++) t += bred[i];
        atomicAdd(out, t * inv_n);
    }
}

// ---------------------------------------------------------------------------
// Row squared-norms of the two target matrices (wave per row).
// ---------------------------------------------------------------------------
__global__ __launch_bounds__(256) void norms_kernel(
    const float* __restrict__ Y, float* __restrict__ tny,
    const float* __restrict__ X, float* __restrict__ tnx, int N)
{
    const int gw = (int)((blockIdx.x * blockDim.x + threadIdx.x) >> 6);
    const int ln = threadIdx.x & 63;
    float s = 0.f;
    if (gw < N) {
        const float* p = Y + (size_t)gw * 120;
        for (int d = ln; d < 120; d += 64) s = fmaf(p[d], p[d], s);
        #pragma unroll
        for (int o = 32; o > 0; o >>= 1) s += __shfl_down(s, o);
        if (ln == 0) tny[gw] = s;
    } else if (gw < 2 * N) {
        const int r = gw - N;
        const float* p = X + (size_t)r * 100;
        for (int d = ln; d < 100; d += 64) s = fmaf(p[d], p[d], s);
        #pragma unroll
        for (int o = 32; o > 0; o >>= 1) s += __shfl_down(s, o);
        if (ln == 0) tnx[r] = s;
    }
}

// ---------------------------------------------------------------------------
// fp32 NxD -> bf16 Nx128 zero-padded; col 127 carries tn[row] (|t|^2).
// ---------------------------------------------------------------------------
__global__ __launch_bounds__(256) void conv_pad(
    const float* __restrict__ src, int D, const float* __restrict__ tn,
    unsigned short* __restrict__ dst, int N)
{
    const int t = blockIdx.x * 256 + threadIdx.x;
    if (t >= N * 128) return;
    const int r = t >> 7, c = t & 127;
    float v = 0.f;
    if (c < D) v = src[(size_t)r * D + c];
    else if (c == 127) v = tn[r];
    dst[t] = f2bf(v);
}

// ---------------------------------------------------------------------------
// Gather rows of MAP, scale by -2, bf16 Kx128 zero-padded; col 127 = 1.0.
// ---------------------------------------------------------------------------
__global__ __launch_bounds__(256) void gather_bf(
    const float* __restrict__ src, int D, const int* __restrict__ gidx, int goff,
    unsigned short* __restrict__ dst, int K)
{
    const int t = blockIdx.x * 256 + threadIdx.x;
    if (t >= K * 128) return;
    const int r = t >> 7, c = t & 127;
    float v = 0.f;
    if (c < D) v = -2.f * src[(size_t)gidx[r * 2 + goff] * D + c];
    else if (c == 127) v = 1.f;
    dst[t] = f2bf(v);
}

// ---------------------------------------------------------------------------
// sup_x + sup_y: wave per pair, coalesced row loads, per-block atomic.
// ---------------------------------------------------------------------------
__global__ __launch_bounds__(256) void sup_kernel(
    const float* __restrict__ xm, const float* __restrict__ ym,
    const float* __restrict__ xw, const float* __restrict__ yw,
    const int* __restrict__ im, int K, float* __restrict__ out, float inv_k)
{
    const int gw = (int)((blockIdx.x * 256 + threadIdx.x) >> 6);
    const int ln = threadIdx.x & 63;
    const int wv = threadIdx.x >> 6;
    float cnt = 0.f;
    if (gw < K) {
        const int xi = im[2 * gw], yi = im[2 * gw + 1];
        const float* a = xm + (size_t)xi * 120;
        const float* b = yw + (size_t)yi * 120;
        float s1 = 0.f;
        for (int d = ln; d < 120; d += 64) { const float df = a[d] - b[d]; s1 = fmaf(df, df, s1); }
        const float* c = ym + (size_t)yi * 100;
        const float* e = xw + (size_t)xi * 100;
        float s2 = 0.f;
        for (int d = ln; d < 100; d += 64) { const float df = c[d] - e[d]; s2 = fmaf(df, df, s2); }
        #pragma unroll
        for (int o = 32; o > 0; o >>= 1) { s1 += __shfl_down(s1, o); s2 += __shfl_down(s2, o); }
        if (ln == 0) cnt = sqrtf(s1) + sqrtf(s2);
    }
    __shared__ float wsum[4];
    if (ln == 0) wsum[wv] = cnt;
    __syncthreads();
    if (threadIdx.x == 0) {
        const float t = wsum[0] + wsum[1] + wsum[2] + wsum[3];
        if (t != 0.f) atomicAdd(out, t * inv_k);
    }
}

// ---------------------------------------------------------------------------
// MFMA 1-NN (unchanged from R3). Block = 256 A rows; B tiles (32x128 bf16)
// double-buffered in LDS, shared by 4 waves. acc = tn[j] - 2 a.t_j directly
// (col127 trick). Argmin via mantissa packing of j>>4 + v_min_f32.
// ---------------------------------------------------------------------------
__global__ __launch_bounds__(256, 3) void nn_mfma(
    const unsigned short* __restrict__ A,
    const unsigned short* __restrict__ T,
    int Ntgt, int K,
    float* __restrict__ pmin, int* __restrict__ pidx)
{
    constexpr int BS = 136;
    __shared__ unsigned short bsm[2][32 * BS];
    __shared__ float rm[4][64][17];

    const int tid = threadIdx.x;
    const int wv = tid >> 6, ln = tid & 63;
    const int col = ln & 15, quad = ln >> 4;
    const int k0 = blockIdx.x * 256;
    const int jstart = blockIdx.y * CHUNK;
    const int jend = min(jstart + CHUNK, Ntgt);
    const int nt = (jend - jstart + 31) >> 5;

    bf16x8 afrag[4][4];
    #pragma unroll
    for (int t = 0; t < 4; t++) {
        const int ar = min(k0 + wv * 64 + t * 16 + col, K - 1);
        const unsigned short* ab = A + (size_t)ar * 128 + quad * 8;
        #pragma unroll
        for (int s = 0; s < 4; s++)
            afrag[t][s] = *reinterpret_cast<const bf16x8*>(ab + s * 32);
    }

    float m[4][4];
    #pragma unroll
    for (int t = 0; t < 4; t++)
        #pragma unroll
        for (int r = 0; r < 4; r++) m[t][r] = __builtin_inff();

    const unsigned bigw = ((unsigned)f2bf(1e30f)) << 16;

    {
        #pragma unroll
        for (int half = 0; half < 2; half++) {
            const int c = tid + half * 256;
            const int r = c >> 4, off = c & 15;
            const int j = jstart + r;
            uint4 v;
            if (j < jend) v = reinterpret_cast<const uint4*>(T + (size_t)j * 128)[off];
            else { v.x = 0; v.y = 0; v.z = 0; v.w = (off == 15) ? bigw : 0u; }
            *reinterpret_cast<uint4*>(&bsm[0][r * BS + off * 8]) = v;
        }
    }
    __syncthreads();

    for (int ti = 0; ti < nt; ti++) {
        const int cur = ti & 1;
        const bool have = (ti + 1 < nt);
        uint4 v0, v1;
        if (have) {
            #pragma unroll
            for (int half = 0; half < 2; half++) {
                const int c = tid + half * 256;
                const int r = c >> 4, off = c & 15;
                const int j = jstart + (ti + 1) * 32 + r;
                uint4 v;
                if (j < jend) v = reinterpret_cast<const uint4*>(T + (size_t)j * 128)[off];
                else { v.x = 0; v.y = 0; v.z = 0; v.w = (off == 15) ? bigw : 0u; }
                if (half == 0) v0 = v; else v1 = v;
            }
        }

        const unsigned short* buf = bsm[cur];
        const unsigned lowbase = (unsigned)((jstart + ti * 32) >> 4);
        #pragma unroll
        for (int sub = 0; sub < 2; sub++) {
            bf16x8 bfr[4];
            const unsigned short* bb = buf + (sub * 16 + col) * BS + quad * 8;
            #pragma unroll
            for (int s = 0; s < 4; s++)
                bfr[s] = *reinterpret_cast<const bf16x8*>(bb + s * 32);
            const unsigned low = lowbase + sub;
            #pragma unroll
            for (int t = 0; t < 4; t++) {
                f32x4 acc = {0.f, 0.f, 0.f, 0.f};
                #pragma unroll
                for (int s = 0; s < 4; s++)
                    acc = __builtin_amdgcn_mfma_f32_16x16x32_bf16(afrag[t][s], bfr[s], acc, 0, 0, 0);
                #pragma unroll
                for (int r = 0; r < 4; r++) {
                    const unsigned u = (__float_as_uint(acc[r]) & 0xFFFFF800u) | low;
                    m[t][r] = fminf(m[t][r], __uint_as_float(u));
                }
            }
        }

        if (have) {
            {
                const int c = tid, r = c >> 4, off = c & 15;
                *reinterpret_cast<uint4*>(&bsm[cur ^ 1][r * BS + off * 8]) = v0;
            }
            {
                const int c = tid + 256, r = c >> 4, off = c & 15;
                *reinterpret_cast<uint4*>(&bsm[cur ^ 1][r * BS + off * 8]) = v1;
            }
        }
        __syncthreads();
    }

    #pragma unroll
    for (int t = 0; t < 4; t++)
        #pragma unroll
        for (int r = 0; r < 4; r++)
            rm[wv][t * 16 + quad * 4 + r][col] = m[t][r];
    __syncthreads();

    const int k = k0 + tid;
    if (k < K) {
        const int w = tid >> 6, rr = tid & 63;
        float best = rm[w][rr][0];
        int bc = 0;
        #pragma unroll
        for (int c = 1; c < 16; c++) {
            const float v = rm[w][rr][c];
            if (v < best) { best = v; bc = c; }
        }
        const int j = (int)(((__float_as_uint(best) & 0x7FFu) << 4) | (unsigned)bc);
        pmin[(size_t)k * NC + blockIdx.y] = best;
        pidx[(size_t)k * NC + blockIdx.y] = j;
    }
}

// ---------------------------------------------------------------------------
// Finish both mismatch terms (unchanged from R3).
// ---------------------------------------------------------------------------
__global__ __launch_bounds__(256) void finish2(
    const float* __restrict__ xm, const float* __restrict__ ym,
    const float* __restrict__ xw, const float* __restrict__ yw,
    const int* __restrict__ im,
    const float* __restrict__ pmin_fx, const int* __restrict__ pidx_fx,
    const float* __restrict__ pmin_gy, const int* __restrict__ pidx_gy,
    int K, float* __restrict__ out, float inv_k)
{
    const int gw = (int)((blockIdx.x * 256 + threadIdx.x) >> 6);
    const int ln = threadIdx.x & 63;
    const int wvi = threadIdx.x >> 6;
    float cnt = 0.f;
    if (gw < 2 * K) {
        const int dir = (gw >= K) ? 1 : 0;
        const int kk = dir ? gw - K : gw;
        const float* pm = dir ? pmin_gy : pmin_fx;
        const int*   pi = dir ? pidx_gy : pidx_fx;

        float v = (ln < NC) ? pm[(size_t)kk * NC + ln] : __builtin_inff();
        int  ii = (ln < NC) ? pi[(size_t)kk * NC + ln] : 0x7fffffff;
        #pragma unroll
        for (int o = 8; o >= 1; o >>= 1) {
            const float ov = __shfl_down(v, o);
            const int   oi = __shfl_down(ii, o);
            if (ov < v || (ov == v && oi < ii)) { v = ov; ii = oi; }
        }
        const int bi = __shfl(ii, 0);
        const int src = im[2 * kk + dir];
        const float* a = dir ? (ym + (size_t)src * 100) : (xm + (size_t)src * 120);
        const float* t = dir ? (xw + (size_t)bi * 100) : (yw + (size_t)bi * 120);
        const int D = dir ? 100 : 120;
        float s = 0.f;
        for (int d = ln; d < D; d += 64) { const float df = a[d] - t[d]; s = fmaf(df, df, s); }
        #pragma unroll
        for (int o = 32; o > 0; o >>= 1) s += __shfl_down(s, o);
        if (ln == 0) {
            const float dist = sqrtf(s);
            cnt = (ceilf(dist) - floorf(dist)) * ((bi != src) ? 1.f : 0.f);
        }
    }
    __shared__ float wsum[4];
    if (ln == 0) wsum[wvi] = cnt;
    __syncthreads();
    if (threadIdx.x == 0) {
        const float t = wsum[0] + wsum[1] + wsum[2] + wsum[3];
        if (t != 0.f) atomicAdd(out, t * inv_k);
    }
}

// ---------------------------------------------------------------------------
extern "C" void kernel_launch(void* const* d_in, const int* in_sizes, int n_in,
                              void* d_out, int out_size, void* d_ws, size_t ws_size,
                              hipStream_t stream)
{
    const float* xw    = (const float*)d_in[0];
    const float* yw    = (const float*)d_in[1];
    const float* fx_w1 = (const float*)d_in[2];
    const float* fx_b1 = (const float*)d_in[3];
    const float* fx_w2 = (const float*)d_in[4];
    const float* fx_b2 = (const float*)d_in[5];
    const float* gy_w1 = (const float*)d_in[6];
    const float* gy_b1 = (const float*)d_in[7];
    const float* gy_w2 = (const float*)d_in[8];
    const float* gy_b2 = (const float*)d_in[9];
    const int*   imap  = (const int*)d_in[10];
    float* out = (float*)d_out;
    float* ws  = (float*)d_ws;

    constexpr int N = NPTS, K = KPAIR;

    float* xm      = ws;                           // N*120
    float* ym      = xm + (size_t)N * 120;         // N*100
    float* tn_y    = ym + (size_t)N * 100;         // N
    float* tn_x    = tn_y + N;                     // N
    float* pmin_fx = tn_x + N;                     // K*NC
    int*   pidx_fx = (int*)(pmin_fx + (size_t)K * NC);
    float* pmin_gy = (float*)(pidx_fx + (size_t)K * NC);
    int*   pidx_gy = (int*)(pmin_gy + (size_t)K * NC);
    unsigned short* ybf = (unsigned short*)(pidx_gy + (size_t)K * NC); // N*128
    unsigned short* xbf = ybf + (size_t)N * 128;
    unsigned short* axf = xbf + (size_t)N * 128;   // K*128
    unsigned short* ayf = axf + (size_t)K * 128;
    unsigned short* wp_fx1 = ayf + (size_t)K * 128;  // 28*512
    unsigned short* wp_fx2 = wp_fx1 + 28 * 512;      // 32*512
    unsigned short* wp_gy1 = wp_fx2 + 32 * 512;      // 28*512
    unsigned short* wp_gy2 = wp_gy1 + 28 * 512;      // 28*512

    hipMemsetAsync(d_out, 0, sizeof(float), stream);

    norms_kernel<<<(2 * N * 64) / 256, 256, 0, stream>>>(yw, tn_y, xw, tn_x, N);

    // bf16 panels of the raw embeddings (col 127 = |t|^2; killed by W padding
    // when used as MLP input)
    conv_pad<<<(N * 128) / 256, 256, 0, stream>>>(yw, 120, tn_y, ybf, N);
    conv_pad<<<(N * 128) / 256, 256, 0, stream>>>(xw, 100, tn_x, xbf, N);

    // fragment-ordered bf16 weight panels
    w_prep<<<116, 64, 0, stream>>>(fx_w1, wp_fx1, fx_w2, wp_fx2, gy_w1, wp_gy1, gy_w2, wp_gy2);

    // fused MLP chains: forward map (store) + cycle norm (atomic)
    const int gm = (N + 63) / 64;
    mlp_fused<100, 120, 8, 7><<<gm, 256, 0, stream>>>(
        xbf, xw, wp_fx1, fx_b1, wp_fx2, fx_b2, wp_gy1, gy_b1, wp_gy2, gy_b2,
        xm, out, 1.f / N, N);
    mlp_fused<120, 100, 7, 8><<<gm, 256, 0, stream>>>(
        ybf, yw, wp_gy1, gy_b1, wp_gy2, gy_b2, wp_fx1, fx_b1, wp_fx2, fx_b2,
        ym, out, 1.f / N, N);

    sup_kernel<<<(K * 64) / 256, 256, 0, stream>>>(
        xm, ym, xw, yw, imap, K, out, 1.f / K);

    // gathered query panels (scaled -2, col 127 = 1)
    gather_bf<<<(K * 128) / 256, 256, 0, stream>>>(xm, 120, imap, 0, axf, K);
    gather_bf<<<(K * 128) / 256, 256, 0, stream>>>(ym, 100, imap, 1, ayf, K);

    // MFMA 1-NN
    dim3 g1((K + 255) / 256, NC);
    nn_mfma<<<g1, 256, 0, stream>>>(axf, ybf, N, K, pmin_fx, pidx_fx);
    nn_mfma<<<g1, 256, 0, stream>>>(ayf, xbf, N, K, pmin_gy, pidx_gy);

    finish2<<<(2 * K * 64) / 256, 256, 0, stream>>>(
        xm, ym, xw, yw, imap, pmin_fx, pidx_fx, pmin_gy, pidx_gy, K, out, 1.f / K);
}

// Round 5
// 245.404 us; speedup vs baseline: 12.4448x; 1.3631x over previous
//
#include <hip/hip_runtime.h>
#include <hip/hip_bf16.h>
#include <math.h>

#define HIDDEN 100

typedef __attribute__((ext_vector_type(8))) short bf16x8;
typedef __attribute__((ext_vector_type(4))) float f32x4;

__device__ inline unsigned short f2bf(float v) {
    union { float f; unsigned u; } x; x.f = v;
    unsigned r = x.u + 0x7fff + ((x.u >> 16) & 1);   // RNE
    return (unsigned short)(r >> 16);
}

constexpr int NPTS  = 25000;
constexpr int KPAIR = 8000;
constexpr int NC    = 16;
constexpr int CHUNK = 1568;   // multiple of 32, 16*1568 = 25088 >= 25000
constexpr int HS    = 136;    // LDS H-slab stride (shorts)
constexpr int NB_SUP = 2000;  // sup partial blocks
constexpr int GM     = (NPTS + 63) / 64;   // 391 mlp blocks per dir
constexpr int NB_MLP = 2 * GM;

// ---------------------------------------------------------------------------
// prep: per row (wave): squared norm -> tn, and bf16x128 padded row with
// col127 = |row|^2. gw < N: yw (D=120) -> tn_y/ybf; else xw (D=100) -> tn_x/xbf.
// ---------------------------------------------------------------------------
__global__ __launch_bounds__(256) void prep_kernel(
    const float* __restrict__ YW, float* __restrict__ tny, unsigned short* __restrict__ ybf,
    const float* __restrict__ XW, float* __restrict__ tnx, unsigned short* __restrict__ xbf,
    int N)
{
    const int gw = (int)((blockIdx.x * blockDim.x + threadIdx.x) >> 6);
    const int ln = threadIdx.x & 63;
    if (gw >= 2 * N) return;
    const int isY = (gw < N);
    const int r = isY ? gw : gw - N;
    const int D = isY ? 120 : 100;
    const float* src = (isY ? YW : XW) + (size_t)r * D;
    unsigned short* dst = (isY ? ybf : xbf) + (size_t)r * 128;

    const float v0 = (ln < D) ? src[ln] : 0.f;
    const float v1 = (ln + 64 < D) ? src[ln + 64] : 0.f;
    float s = fmaf(v0, v0, v1 * v1);
    #pragma unroll
    for (int o = 1; o < 64; o <<= 1) s += __shfl_xor(s, o);
    if (ln == 0) (isY ? tny : tnx)[r] = s;

    dst[ln] = f2bf(v0);
    dst[ln + 64] = (ln == 63) ? f2bf(s) : f2bf(v1);
}

// ---------------------------------------------------------------------------
// Weight prep -> fragment-ordered bf16 panels, zero-padded (unchanged).
// ---------------------------------------------------------------------------
__global__ __launch_bounds__(64) void w_prep(
    const float* __restrict__ W1, unsigned short* __restrict__ P1,
    const float* __restrict__ W2, unsigned short* __restrict__ P2,
    const float* __restrict__ W3, unsigned short* __restrict__ P3,
    const float* __restrict__ W4, unsigned short* __restrict__ P4)
{
    int b = blockIdx.x;
    const float* W; unsigned short* P; int DK, DN, NT;
    if (b < 28)      {          W = W1; P = P1; DK = 100; DN = 100; NT = 7; }
    else if (b < 60) { b -= 28; W = W2; P = P2; DK = 100; DN = 120; NT = 8; }
    else if (b < 88) { b -= 60; W = W3; P = P3; DK = 120; DN = 100; NT = 7; }
    else             { b -= 88; W = W4; P = P4; DK = 100; DN = 100; NT = 7; }
    const int kt = b / NT, nt = b - kt * NT;
    const int ln = threadIdx.x;
    const int n  = nt * 16 + (ln & 15);
    const int k0 = kt * 32 + (ln >> 4) * 8;
    unsigned short* dst = P + ((size_t)(kt * NT + nt) * 64 + ln) * 8;
    #pragma unroll
    for (int j = 0; j < 8; j++) {
        const int k = k0 + j;
        const float f = (k < DK && n < DN) ? W[k * DN + n] : 0.f;
        dst[j] = f2bf(f);
    }
}

// ---------------------------------------------------------------------------
// MFMA stage helpers (layouts HW-verified: absmax 0.0 R2-R4).
// ---------------------------------------------------------------------------
template<int NT>
__device__ inline void run_stage(const bf16x8 af[4], const unsigned short* __restrict__ WP,
                                 int ln, f32x4 acc[NT])
{
    #pragma unroll
    for (int nt = 0; nt < NT; nt++) acc[nt] = (f32x4){0.f, 0.f, 0.f, 0.f};
    #pragma unroll
    for (int kt = 0; kt < 4; kt++) {
        #pragma unroll
        for (int nt = 0; nt < NT; nt++) {
            const bf16x8 wf = *reinterpret_cast<const bf16x8*>(WP + ((size_t)(kt * NT + nt) * 64 + ln) * 8);
            acc[nt] = __builtin_amdgcn_mfma_f32_16x16x32_bf16(af[kt], wf, acc[nt], 0, 0, 0);
        }
    }
}

template<int NT, int DN, bool RELU>
__device__ inline void pack_h(const f32x4 acc[NT], const float* __restrict__ B,
                              unsigned short* __restrict__ Hs, int col, int quad)
{
    #pragma unroll
    for (int nt = 0; nt < NT; nt++) {
        const int n = nt * 16 + col;
        const float b = (n < DN) ? B[n] : 0.f;
        #pragma unroll
        for (int r = 0; r < 4; r++) {
            float v = acc[nt][r] + b;
            if (RELU) v = fmaxf(v, 0.f);
            Hs[(quad * 4 + r) * HS + n] = f2bf(v);
        }
    }
}

template<int NT, int DN>
__device__ inline void store_pack(const f32x4 acc[NT], const float* __restrict__ B,
                                  float* __restrict__ Y, unsigned short* __restrict__ Hs,
                                  int rowbase, int col, int quad, int N)
{
    #pragma unroll
    for (int nt = 0; nt < NT; nt++) {
        const int n = nt * 16 + col;
        const float b = (n < DN) ? B[n] : 0.f;
        #pragma unroll
        for (int r = 0; r < 4; r++) {
            const float v = acc[nt][r] + b;
            const int row = rowbase + quad * 4 + r;
            if (n < DN && row < N) Y[(size_t)row * DN + n] = v;
            Hs[(quad * 4 + r) * HS + n] = f2bf(v);
        }
    }
}

__device__ inline void load_haf(const unsigned short* __restrict__ Hs, int col, int quad,
                                bf16x8 af[4])
{
    const unsigned short* p = Hs + col * HS + quad * 8;
    #pragma unroll
    for (int kt = 0; kt < 4; kt++)
        af[kt] = *reinterpret_cast<const bf16x8*>(p + kt * 32);
}

template<int NT, int DN>
__device__ inline float norm_stage(const f32x4 acc[NT], const float* __restrict__ B,
                                   const float* __restrict__ REF,
                                   int rowbase, int col, int quad, int N)
{
    float ra[4] = {0.f, 0.f, 0.f, 0.f};
    #pragma unroll
    for (int nt = 0; nt < NT; nt++) {
        const int n = nt * 16 + col;
        if (n < DN) {
            const float b = B[n];
            #pragma unroll
            for (int r = 0; r < 4; r++) {
                const int row = rowbase + quad * 4 + r;
                if (row < N) {
                    const float d = acc[nt][r] + b - REF[(size_t)row * DN + n];
                    ra[r] = fmaf(d, d, ra[r]);
                }
            }
        }
    }
    #pragma unroll
    for (int o = 1; o < 16; o <<= 1) {
        #pragma unroll
        for (int r = 0; r < 4; r++) ra[r] += __shfl_xor(ra[r], o);
    }
    float s = 0.f;
    if (col == 0) {
        #pragma unroll
        for (int r = 0; r < 4; r++)
            if (rowbase + quad * 4 + r < N) s += sqrtf(ra[r]);
    }
    return s;
}

// ---------------------------------------------------------------------------
// Fused 4-stage MLP chain (unchanged structure; partial -> ws, no atomic).
// ---------------------------------------------------------------------------
template<int DIN, int DMID, int NT2, int NTF>
__global__ __launch_bounds__(256) void mlp_fused(
    const unsigned short* __restrict__ Xbf,
    const float* __restrict__ XREF,
    const unsigned short* __restrict__ WP1, const float* __restrict__ B1,
    const unsigned short* __restrict__ WP2, const float* __restrict__ B2,
    const unsigned short* __restrict__ WP3, const float* __restrict__ B3,
    const unsigned short* __restrict__ WP4, const float* __restrict__ B4,
    float* __restrict__ Y,
    float* __restrict__ part, int N)
{
    __shared__ unsigned short H[4][16 * HS];
    __shared__ float bred[16];

    const int tid = threadIdx.x;
    const int wv = tid >> 6, ln = tid & 63;
    const int col = ln & 15, quad = ln >> 4;
    const int rowbase = blockIdx.x * 64 + wv * 16;

    {
        unsigned* Hz = reinterpret_cast<unsigned*>(H[wv]);
        for (int i = ln; i < 16 * HS / 2; i += 64) Hz[i] = 0u;
    }

    bf16x8 af[4];
    {
        const int r = min(rowbase + col, N - 1);
        const unsigned short* ap = Xbf + (size_t)r * 128 + quad * 8;
        #pragma unroll
        for (int kt = 0; kt < 4; kt++) af[kt] = *reinterpret_cast<const bf16x8*>(ap + kt * 32);
    }

    f32x4 accA[7];
    run_stage<7>(af, WP1, ln, accA);
    pack_h<7, HIDDEN, true>(accA, B1, H[wv], col, quad);
    load_haf(H[wv], col, quad, af);

    f32x4 accB[NT2];
    run_stage<NT2>(af, WP2, ln, accB);
    store_pack<NT2, DMID>(accB, B2, Y, H[wv], rowbase, col, quad, N);
    load_haf(H[wv], col, quad, af);

    run_stage<7>(af, WP3, ln, accA);
    pack_h<7, HIDDEN, true>(accA, B3, H[wv], col, quad);
    load_haf(H[wv], col, quad, af);

    f32x4 accC[NTF];
    run_stage<NTF>(af, WP4, ln, accC);
    const float s = norm_stage<NTF, DIN>(accC, B4, XREF, rowbase, col, quad, N);

    if (col == 0) bred[wv * 4 + quad] = s;
    __syncthreads();
    if (tid == 0) {
        float t = 0.f;
        #pragma unroll
        for (int i = 0; i < 16; i++) t += bred[i];
        part[blockIdx.x] = t;
    }
}

// ---------------------------------------------------------------------------
// sup: wave per pair; block partial -> ws (no contended atomic).
// ---------------------------------------------------------------------------
__global__ __launch_bounds__(256) void sup_kernel(
    const float* __restrict__ xm, const float* __restrict__ ym,
    const float* __restrict__ xw, const float* __restrict__ yw,
    const int* __restrict__ im, int K, float* __restrict__ part)
{
    const int gw = (int)((blockIdx.x * 256 + threadIdx.x) >> 6);
    const int ln = threadIdx.x & 63;
    const int wv = threadIdx.x >> 6;
    float cnt = 0.f;
    if (gw < K) {
        const int xi = im[2 * gw], yi = im[2 * gw + 1];
        const float* a = xm + (size_t)xi * 120;
        const float* b = yw + (size_t)yi * 120;
        float s1 = 0.f;
        for (int d = ln; d < 120; d += 64) { const float df = a[d] - b[d]; s1 = fmaf(df, df, s1); }
        const float* c = ym + (size_t)yi * 100;
        const float* e = xw + (size_t)xi * 100;
        float s2 = 0.f;
        for (int d = ln; d < 100; d += 64) { const float df = c[d] - e[d]; s2 = fmaf(df, df, s2); }
        #pragma unroll
        for (int o = 32; o > 0; o >>= 1) { s1 += __shfl_down(s1, o); s2 += __shfl_down(s2, o); }
        if (ln == 0) cnt = sqrtf(s1) + sqrtf(s2);
    }
    __shared__ float wsum[4];
    if (ln == 0) wsum[wv] = cnt;
    __syncthreads();
    if (threadIdx.x == 0)
        part[blockIdx.x] = wsum[0] + wsum[1] + wsum[2] + wsum[3];
}

// ---------------------------------------------------------------------------
// Gather both query panels (scaled -2, col127=1) in one launch.
// ---------------------------------------------------------------------------
__global__ __launch_bounds__(256) void gather2(
    const float* __restrict__ xm, const float* __restrict__ ym,
    const int* __restrict__ gidx,
    unsigned short* __restrict__ axf, unsigned short* __restrict__ ayf, int K)
{
    const int t = blockIdx.x * 256 + threadIdx.x;
    if (t >= 2 * K * 128) return;
    const int dir = (t >= K * 128);
    const int tt = dir ? t - K * 128 : t;
    const int r = tt >> 7, c = tt & 127;
    const float* src = dir ? ym : xm;
    const int D = dir ? 100 : 120;
    float v = 0.f;
    if (c < D) v = -2.f * src[(size_t)gidx[r * 2 + dir] * D + c];
    else if (c == 127) v = 1.f;
    (dir ? ayf : axf)[tt] = f2bf(v);
}

// ---------------------------------------------------------------------------
// MFMA 1-NN, both directions in one dispatch (blockIdx.z).
// ---------------------------------------------------------------------------
__global__ __launch_bounds__(256, 3) void nn_mfma(
    const unsigned short* __restrict__ A0, const unsigned short* __restrict__ T0,
    float* __restrict__ pm0, int* __restrict__ pi0,
    const unsigned short* __restrict__ A1, const unsigned short* __restrict__ T1,
    float* __restrict__ pm1, int* __restrict__ pi1,
    int Ntgt, int K)
{
    constexpr int BS = 136;
    __shared__ unsigned short bsm[2][32 * BS];
    __shared__ float rm[4][64][17];

    const unsigned short* A = blockIdx.z ? A1 : A0;
    const unsigned short* T = blockIdx.z ? T1 : T0;
    float* pmin = blockIdx.z ? pm1 : pm0;
    int*   pidx = blockIdx.z ? pi1 : pi0;

    const int tid = threadIdx.x;
    const int wv = tid >> 6, ln = tid & 63;
    const int col = ln & 15, quad = ln >> 4;
    const int k0 = blockIdx.x * 256;
    const int jstart = blockIdx.y * CHUNK;
    const int jend = min(jstart + CHUNK, Ntgt);
    const int nt = (jend - jstart + 31) >> 5;

    bf16x8 afrag[4][4];
    #pragma unroll
    for (int t = 0; t < 4; t++) {
        const int ar = min(k0 + wv * 64 + t * 16 + col, K - 1);
        const unsigned short* ab = A + (size_t)ar * 128 + quad * 8;
        #pragma unroll
        for (int s = 0; s < 4; s++)
            afrag[t][s] = *reinterpret_cast<const bf16x8*>(ab + s * 32);
    }

    float m[4][4];
    #pragma unroll
    for (int t = 0; t < 4; t++)
        #pragma unroll
        for (int r = 0; r < 4; r++) m[t][r] = __builtin_inff();

    const unsigned bigw = ((unsigned)f2bf(1e30f)) << 16;

    {
        #pragma unroll
        for (int half = 0; half < 2; half++) {
            const int c = tid + half * 256;
            const int r = c >> 4, off = c & 15;
            const int j = jstart + r;
            uint4 v;
            if (j < jend) v = reinterpret_cast<const uint4*>(T + (size_t)j * 128)[off];
            else { v.x = 0; v.y = 0; v.z = 0; v.w = (off == 15) ? bigw : 0u; }
            *reinterpret_cast<uint4*>(&bsm[0][r * BS + off * 8]) = v;
        }
    }
    __syncthreads();

    for (int ti = 0; ti < nt; ti++) {
        const int cur = ti & 1;
        const bool have = (ti + 1 < nt);
        uint4 v0, v1;
        if (have) {
            #pragma unroll
            for (int half = 0; half < 2; half++) {
                const int c = tid + half * 256;
                const int r = c >> 4, off = c & 15;
                const int j = jstart + (ti + 1) * 32 + r;
                uint4 v;
                if (j < jend) v = reinterpret_cast<const uint4*>(T + (size_t)j * 128)[off];
                else { v.x = 0; v.y = 0; v.z = 0; v.w = (off == 15) ? bigw : 0u; }
                if (half == 0) v0 = v; else v1 = v;
            }
        }

        const unsigned short* buf = bsm[cur];
        const unsigned lowbase = (unsigned)((jstart + ti * 32) >> 4);
        #pragma unroll
        for (int sub = 0; sub < 2; sub++) {
            bf16x8 bfr[4];
            const unsigned short* bb = buf + (sub * 16 + col) * BS + quad * 8;
            #pragma unroll
            for (int s = 0; s < 4; s++)
                bfr[s] = *reinterpret_cast<const bf16x8*>(bb + s * 32);
            const unsigned low = lowbase + sub;
            #pragma unroll
            for (int t = 0; t < 4; t++) {
                f32x4 acc = {0.f, 0.f, 0.f, 0.f};
                #pragma unroll
                for (int s = 0; s < 4; s++)
                    acc = __builtin_amdgcn_mfma_f32_16x16x32_bf16(afrag[t][s], bfr[s], acc, 0, 0, 0);
                #pragma unroll
                for (int r = 0; r < 4; r++) {
                    const unsigned u = (__float_as_uint(acc[r]) & 0xFFFFF800u) | low;
                    m[t][r] = fminf(m[t][r], __uint_as_float(u));
                }
            }
        }

        if (have) {
            {
                const int c = tid, r = c >> 4, off = c & 15;
                *reinterpret_cast<uint4*>(&bsm[cur ^ 1][r * BS + off * 8]) = v0;
            }
            {
                const int c = tid + 256, r = c >> 4, off = c & 15;
                *reinterpret_cast<uint4*>(&bsm[cur ^ 1][r * BS + off * 8]) = v1;
            }
        }
        __syncthreads();
    }

    #pragma unroll
    for (int t = 0; t < 4; t++)
        #pragma unroll
        for (int r = 0; r < 4; r++)
            rm[wv][t * 16 + quad * 4 + r][col] = m[t][r];
    __syncthreads();

    const int k = k0 + tid;
    if (k < K) {
        const int w = tid >> 6, rr = tid & 63;
        float best = rm[w][rr][0];
        int bc = 0;
        #pragma unroll
        for (int c = 1; c < 16; c++) {
            const float v = rm[w][rr][c];
            if (v < best) { best = v; bc = c; }
        }
        const int j = (int)(((__float_as_uint(best) & 0x7FFu) << 4) | (unsigned)bc);
        pmin[(size_t)k * NC + blockIdx.y] = best;
        pidx[(size_t)k * NC + blockIdx.y] = j;
    }
}

// ---------------------------------------------------------------------------
// finish_all: mismatch indicators (no distance recompute: ceil-floor == 1
// a.s. for non-integer distances) + sup partials + mlp partials.
// 64 blocks -> 64 atomics total.
// ---------------------------------------------------------------------------
__global__ __launch_bounds__(256) void finish_all(
    const int* __restrict__ im,
    const float* __restrict__ pm0, const int* __restrict__ pi0,
    const float* __restrict__ pm1, const int* __restrict__ pi1,
    const float* __restrict__ part_sup, const float* __restrict__ part_mlp,
    int K, float* __restrict__ out, float inv_k, float inv_n)
{
    const int gid = blockIdx.x * 256 + threadIdx.x;
    const int stride = gridDim.x * 256;
    float local = 0.f;

    for (int p = gid; p < 2 * K; p += stride) {
        const int dir = (p >= K);
        const int kk = dir ? p - K : p;
        const float* pm = dir ? pm1 : pm0;
        const int*   pi = dir ? pi1 : pi0;
        float best = __builtin_inff();
        int bi = 0x7fffffff;
        #pragma unroll
        for (int c = 0; c < NC; c++) {
            const float v = pm[(size_t)kk * NC + c];
            const int  ii = pi[(size_t)kk * NC + c];
            if (v < best || (v == best && ii < bi)) { best = v; bi = ii; }
        }
        if (bi != im[2 * kk + dir]) local += inv_k;
    }
    for (int i = gid; i < NB_SUP; i += stride) local += part_sup[i] * inv_k;
    for (int i = gid; i < NB_MLP; i += stride) local += part_mlp[i] * inv_n;

    #pragma unroll
    for (int o = 32; o > 0; o >>= 1) local += __shfl_down(local, o);
    __shared__ float wsum[4];
    if ((threadIdx.x & 63) == 0) wsum[threadIdx.x >> 6] = local;
    __syncthreads();
    if (threadIdx.x == 0) {
        const float t = wsum[0] + wsum[1] + wsum[2] + wsum[3];
        if (t != 0.f) atomicAdd(out, t);
    }
}

// ---------------------------------------------------------------------------
extern "C" void kernel_launch(void* const* d_in, const int* in_sizes, int n_in,
                              void* d_out, int out_size, void* d_ws, size_t ws_size,
                              hipStream_t stream)
{
    const float* xw    = (const float*)d_in[0];
    const float* yw    = (const float*)d_in[1];
    const float* fx_w1 = (const float*)d_in[2];
    const float* fx_b1 = (const float*)d_in[3];
    const float* fx_w2 = (const float*)d_in[4];
    const float* fx_b2 = (const float*)d_in[5];
    const float* gy_w1 = (const float*)d_in[6];
    const float* gy_b1 = (const float*)d_in[7];
    const float* gy_w2 = (const float*)d_in[8];
    const float* gy_b2 = (const float*)d_in[9];
    const int*   imap  = (const int*)d_in[10];
    float* out = (float*)d_out;
    float* ws  = (float*)d_ws;

    constexpr int N = NPTS, K = KPAIR;

    float* xm      = ws;                           // N*120
    float* ym      = xm + (size_t)N * 120;         // N*100
    float* tn_y    = ym + (size_t)N * 100;         // N
    float* tn_x    = tn_y + N;                     // N
    float* pmin_fx = tn_x + N;                     // K*NC
    int*   pidx_fx = (int*)(pmin_fx + (size_t)K * NC);
    float* pmin_gy = (float*)(pidx_fx + (size_t)K * NC);
    int*   pidx_gy = (int*)(pmin_gy + (size_t)K * NC);
    unsigned short* ybf = (unsigned short*)(pidx_gy + (size_t)K * NC); // N*128
    unsigned short* xbf = ybf + (size_t)N * 128;
    unsigned short* axf = xbf + (size_t)N * 128;   // K*128
    unsigned short* ayf = axf + (size_t)K * 128;
    unsigned short* wp_fx1 = ayf + (size_t)K * 128;  // 28*512
    unsigned short* wp_fx2 = wp_fx1 + 28 * 512;      // 32*512
    unsigned short* wp_gy1 = wp_fx2 + 32 * 512;      // 28*512
    unsigned short* wp_gy2 = wp_gy1 + 28 * 512;      // 28*512
    float* part_sup = (float*)(wp_gy2 + 28 * 512);   // NB_SUP
    float* part_mlp = part_sup + NB_SUP;             // NB_MLP

    hipMemsetAsync(d_out, 0, sizeof(float), stream);

    prep_kernel<<<(2 * N * 64 + 255) / 256, 256, 0, stream>>>(
        yw, tn_y, ybf, xw, tn_x, xbf, N);

    w_prep<<<116, 64, 0, stream>>>(fx_w1, wp_fx1, fx_w2, wp_fx2, gy_w1, wp_gy1, gy_w2, wp_gy2);

    mlp_fused<100, 120, 8, 7><<<GM, 256, 0, stream>>>(
        xbf, xw, wp_fx1, fx_b1, wp_fx2, fx_b2, wp_gy1, gy_b1, wp_gy2, gy_b2,
        xm, part_mlp, N);
    mlp_fused<120, 100, 7, 8><<<GM, 256, 0, stream>>>(
        ybf, yw, wp_gy1, gy_b1, wp_gy2, gy_b2, wp_fx1, fx_b1, wp_fx2, fx_b2,
        ym, part_mlp + GM, N);

    sup_kernel<<<NB_SUP, 256, 0, stream>>>(xm, ym, xw, yw, imap, K, part_sup);

    gather2<<<(2 * K * 128) / 256, 256, 0, stream>>>(xm, ym, imap, axf, ayf, K);

    dim3 g1((K + 255) / 256, NC, 2);
    nn_mfma<<<g1, 256, 0, stream>>>(axf, ybf, pmin_fx, pidx_fx,
                                    ayf, xbf, pmin_gy, pidx_gy, N, K);

    finish_all<<<64, 256, 0, stream>>>(
        imap, pmin_fx, pidx_fx, pmin_gy, pidx_gy, part_sup, part_mlp,
        K, out, 1.f / K, 1.f / N);
}